// Round 6
// baseline (18658.647 us; speedup 1.0000x reference)
//
#include <hip/hip_runtime.h>
#include <math.h>

#define B_ 40
#define L_ 1000
#define H_ 512
#define A_ 300
#define T_ 20
#define E_ 300
#define V_ 78864
#define START_ 2

#define NBLK 256
#define NTHR 512

// ---------------- workspace layout (float offsets) ----------------
#define OFF_CKH   0ul          /* bf16 copyK, padded [B][L][320] ushort = 6.4M floats */
#define OFF_M1T   6400000ul
#define OFF_M2T   6662144ul
#define OFF_BQK1  6924288ul
#define OFF_BQK2  6924800ul
#define OFF_QK    6925312ul
#define OFF_DEC   6945792ul
#define OFF_ATT1  6966272ul
#define OFF_ATTT  6978272ul
#define OFF_CPART 6990272ul
#define OFF_CSTAT 7113152ul
#define OFF_SCC   7113664ul
#define OFF_STT   7153664ul    /* zero region starts here */
#define OFF_ATT2  7481344ul
#define OFF_SELP  7493344ul
#define OFF_CNT   7616224ul
#define WS_END    7616288ul

struct P {
  const int* enc_in; const float* enc; const unsigned char* mask; const int* inputs;
  const float* embed;
  const float *e1Wih,*e1Whh,*e1b,*e2Wih,*e2Whh,*e2b;
  const float *inW,*inb;
  const float *r1Wih,*r1Whh,*r1b;
  const float *a1Wq,*a1bq,*a1Wk,*a1Wv,*a1bv;
  const float *r2Wih,*r2Whh,*r2b;
  const float *a2Wq,*a2bq,*a2Wk,*a2Wv,*a2bv;
  const float *cW,*cb,*oW,*ob,*scale;
  float* dout;
  unsigned short* copyKh;
  float *M1T,*M2T,*bqk1,*bqk2,*qk,*dec,*att1,*attT,*cpart,*cstat,*scc,*stt,*att2,*selp;
  unsigned* cnt;
};

__device__ __forceinline__ float sigm(float x){ return 1.0f/(1.0f+expf(-x)); }

__device__ __forceinline__ float wredSum(float v){
#pragma unroll
  for(int o=32;o>0;o>>=1) v+=__shfl_xor(v,o);
  return v;
}
__device__ __forceinline__ float wredMax(float v){
#pragma unroll
  for(int o=32;o>0;o>>=1) v=fmaxf(v,__shfl_xor(v,o));
  return v;
}
__device__ __forceinline__ unsigned short f2bf(float f){
  unsigned u=__float_as_uint(f);
  u=(u+0x7fffu+((u>>16)&1u))>>16;
  return (unsigned short)u;
}

// device-scope grid barrier: monotone counter, memset to 0 before launch
__device__ __forceinline__ void gbar(unsigned* cnt, unsigned target){
  __syncthreads();
  if(threadIdx.x==0){
    __hip_atomic_fetch_add(cnt,1u,__ATOMIC_RELEASE,__HIP_MEMORY_SCOPE_AGENT);
    while(__hip_atomic_load(cnt,__ATOMIC_RELAXED,__HIP_MEMORY_SCOPE_AGENT)<target){
      __builtin_amdgcn_s_sleep(1);
    }
    (void)__hip_atomic_load(cnt,__ATOMIC_ACQUIRE,__HIP_MEMORY_SCOPE_AGENT);
  }
  __syncthreads();
}

// batched-40 GEMV accumulate over one input segment.
template<typename SRC>
static __device__ __forceinline__ void gv_accum(float* xs,int K,const float* Wrow,
    float& acc,int lane,int kq,int nq,SRC src){
  for(int k0=0;k0<K;k0+=256){
    int ch=min(256,K-k0);
    __syncthreads();
    for(int i=threadIdx.x;i<40*ch;i+=NTHR){
      int bb=i/ch, kk=i-bb*ch;
      xs[bb*257+kk]=src(bb,k0+kk);
    }
    __syncthreads();
    if(lane<40){
#pragma unroll 4
      for(int k=kq;k<ch;k+=nq) acc+=Wrow[k0+k]*xs[lane*257+k];
    }
  }
}

// one LSTM cell for all 40 b: block owns 2 units x 4 gates (8 waves)
static __device__ void lstm_ph(const P& p,float* SH,float* gld,int t,
    const float* Wih,int XD,const float* Whh,const float* bias,
    const float* xvec,bool gather,
    const float* hr,const float* cr,float* hw,float* cw){
  int tid=threadIdx.x,w=tid>>6,lane=tid&63;
  int gate=w&3,usub=w>>2;
  int row=gate*H_+(blockIdx.x*2+usub);
  int rowu=__builtin_amdgcn_readfirstlane(row);
  float acc=bias[rowu];
  const float* W1=Wih+(size_t)rowu*XD;
  if(gather){
    const int* inp=p.inputs; const float* emb=p.embed; int tt=t;
    gv_accum(SH,XD,W1,acc,lane,0,1,[=](int bb,int kk)->float{
      int si=(tt==0)?START_:inp[bb*T_+tt-1];
      return emb[(size_t)si*E_+kk];});
  }else{
    gv_accum(SH,XD,W1,acc,lane,0,1,[=](int bb,int kk)->float{
      return xvec[(size_t)bb*XD+kk];});
  }
  const float* W2=Whh+(size_t)rowu*H_;
  gv_accum(SH,H_,W2,acc,lane,0,1,[=](int bb,int kk)->float{
    return hr[bb*H_+kk];});
  gld[w*64+lane]=acc;
  __syncthreads();
  if(w<2&&lane<40){
    int u=blockIdx.x*2+w,b=lane;
    float gi=gld[(w*4+0)*64+b],gf=gld[(w*4+1)*64+b],gg=gld[(w*4+2)*64+b],go=gld[(w*4+3)*64+b];
    float c=cr[b*H_+u];
    float cn=sigm(gf)*c+sigm(gi)*tanhf(gg);
    hw[b*H_+u]=sigm(go)*tanhf(cn);
    cw[b*H_+u]=cn;
  }
  __syncthreads();
}

// qk[b][h'] = bqk[h'] + sum_h hsrc[b][h] * MT[h'][h]
static __device__ void qk_ph(const P& p,float* SH,const float* hsrc,
    const float* MT,const float* bqk){
  int tid=threadIdx.x;
  if(blockIdx.x>=240) return;
  int b=blockIdx.x/6, j=blockIdx.x%6;
  SH[tid]=hsrc[b*H_+tid];
  __syncthreads();
  int h0=j*86, hc=min(86,H_-h0);
  if(tid<hc){
    int hp=h0+tid;
    float a=bqk[hp];
    const float4* mr=(const float4*)(MT+(size_t)hp*H_);
#pragma unroll 8
    for(int i=0;i<H_/4;i++){
      float4 m4=mr[i];
      a+=SH[4*i]*m4.x+SH[4*i+1]*m4.y+SH[4*i+2]*m4.z+SH[4*i+3]*m4.w;
    }
    p.qk[b*H_+hp]=a;
  }
}

// fused scores + online-softmax ctx partial, staged 16-row tiles for MLP
static __device__ void scctx_ph(const P& p,float* SH){
  int tid=threadIdx.x,w=tid>>6,lane=tid&63;
  if(blockIdx.x>=240) return;
  int b=blockIdx.x/6, j=blockIdx.x%6;
  int l0=j*167, lcnt=min(167,L_-l0);
  const float* qrow=p.qk+b*H_;
  float4 q0=*(const float4*)(qrow+lane*8);
  float4 q1=*(const float4*)(qrow+lane*8+4);
  float* tile=SH;            // [16*512]
  float* sc16=SH+8192;       // [16]
  float m=-3.0e38f,S=0.f,acc=0.f;
  for(int t0=0;t0<lcnt;t0+=16){
    int tc=min(16,lcnt-t0);
    __syncthreads();
    { // stage tc rows (coalesced float4, fully independent loads)
      const float4* src=(const float4*)(p.enc+((size_t)(b*L_+l0+t0))*H_);
      float4* dst=(float4*)tile;
      for(int i=tid;i<tc*128;i+=NTHR) dst[i]=src[i];
    }
    __syncthreads();
    // scores: wave w -> rows w*2, w*2+1
#pragma unroll
    for(int r=0;r<2;r++){
      int row=w*2+r;
      float sc;
      if(row<tc){
        const float4* er=(const float4*)(tile+row*512);
        float4 e0=er[lane*2], e1=er[lane*2+1];
        float pp=q0.x*e0.x+q0.y*e0.y+q0.z*e0.z+q0.w*e0.w
                +q1.x*e1.x+q1.y*e1.y+q1.z*e1.z+q1.w*e1.w;
        pp=wredSum(pp);
        sc=p.mask[b*L_+l0+t0+row]?-1e9f:pp;
      } else sc=-1e30f;
      if(lane==0) sc16[row]=sc;
    }
    __syncthreads();
    // batched online-softmax merge; each thread owns h=tid
    float tm=-3.0e38f;
    for(int r=0;r<tc;r++) tm=fmaxf(tm,sc16[r]);
    float mn=fmaxf(m,tm);
    float scl=expf(m-mn);
    float Sadd=0.f, aadd=0.f;
    for(int r=0;r<tc;r++){
      float pe=expf(sc16[r]-mn);
      Sadd+=pe;
      aadd+=pe*tile[r*512+tid];
    }
    S=S*scl+Sadd;
    acc=acc*scl+aadd;
    m=mn;
  }
  p.cpart[(size_t)(b*6+j)*H_+tid]=acc;
  if(tid==0){p.cstat[(b*6+j)*2]=m; p.cstat[(b*6+j)*2+1]=S;}
}

// combine 6 ctx partials, project through Wv (+bv) -> att
static __device__ void atto_ph(const P& p,float* SH,const float* Wv,const float* bv,bool ADD){
  int tid=threadIdx.x;
  if(blockIdx.x>=40) return;
  int b=blockIdx.x;
  float mb=-3.0e38f;
#pragma unroll
  for(int j=0;j<6;j++) mb=fmaxf(mb,p.cstat[(b*6+j)*2]);
  float Sb=0.f;
#pragma unroll
  for(int j=0;j<6;j++) Sb+=p.cstat[(b*6+j)*2+1]*expf(p.cstat[(b*6+j)*2]-mb);
  float inv=1.0f/Sb;
  float cx=0.f;
#pragma unroll
  for(int j=0;j<6;j++) cx+=expf(p.cstat[(b*6+j)*2]-mb)*p.cpart[(size_t)(b*6+j)*H_+tid];
  SH[tid]=cx*inv;
  __syncthreads();
  if(tid<A_){
    float a=bv[tid];
    const float4* wr=(const float4*)(Wv+(size_t)tid*H_);
#pragma unroll 8
    for(int i=0;i<H_/4;i++){
      float4 w4=wr[i];
      a+=SH[4*i]*w4.x+SH[4*i+1]*w4.y+SH[4*i+2]*w4.z+SH[4*i+3]*w4.w;
    }
    if(ADD){ a+=p.att1[b*A_+tid]; p.att2[b*A_+tid]=a; p.attT[tid*B_+b]=a; }
    else p.att1[b*A_+tid]=a;
  }
}

// copy scores from bf16 copyK (16B/lane), att hoisted in regs
static __device__ void copysc_ph(const P& p){
  int tid=threadIdx.x,w=tid>>6,lane=tid&63;
  if(blockIdx.x>=240) return;
  int b=blockIdx.x/6, j=blockIdx.x%6;
  int l0=j*167, lcnt=min(167,L_-l0);
  float ar[8];
#pragma unroll
  for(int q=0;q<8;q++){
    int a=lane*8+q;
    ar[q]=(lane<40&&a<A_)? p.att2[b*A_+a] : 0.f;
  }
  for(int l=l0+w;l<l0+lcnt;l+=8){
    float pp=0.f;
    if(lane<40){
      const uint4* cr=(const uint4*)(p.copyKh+((size_t)(b*L_+l))*320);
      uint4 kk=cr[lane];
      pp =ar[0]*__uint_as_float(kk.x<<16)+ar[1]*__uint_as_float(kk.x&0xffff0000u);
      pp+=ar[2]*__uint_as_float(kk.y<<16)+ar[3]*__uint_as_float(kk.y&0xffff0000u);
      pp+=ar[4]*__uint_as_float(kk.z<<16)+ar[5]*__uint_as_float(kk.z&0xffff0000u);
      pp+=ar[6]*__uint_as_float(kk.w<<16)+ar[7]*__uint_as_float(kk.w&0xffff0000u);
    }
    pp=wredSum(pp);
    if(lane==0) p.scc[b*L_+l]=p.mask[b*L_+l]?-1e9f:pp;
  }
}

// vocab rows v0..v0+311: W tile staged with float4 loads, attT via uniform s_load
static __device__ void vocab_ph(const P& p,float* SH,int t){
  int tid=threadIdx.x;
  int v0=blockIdx.x*312;
  if(v0>=V_) return;
  int vcnt=min(312,V_-v0);
  float acc[40];
#pragma unroll
  for(int b=0;b<40;b++) acc[b]=0.f;
  for(int c=0;c<10;c++){
    int a0=c*32, aw=min(32,A_-a0);
    int awf4=aw>>2;
    __syncthreads();
    for(int i=tid;i<vcnt*awf4;i+=NTHR){
      int vr=i/awf4, f=i-vr*awf4;
      float4 x=*(const float4*)(p.oW+(size_t)(v0+vr)*A_+a0+f*4);
      float* dst=&SH[vr*33+f*4];
      dst[0]=x.x;dst[1]=x.y;dst[2]=x.z;dst[3]=x.w;
    }
    __syncthreads();
    if(tid<vcnt){
      for(int ac=0;ac<aw;ac++){
        float wv=SH[tid*33+ac];
        const float* at=p.attT+(a0+ac)*B_;
#pragma unroll
        for(int bq=0;bq<10;bq++){
          float4 t4=*(const float4*)(at+bq*4);
          acc[bq*4+0]+=wv*t4.x; acc[bq*4+1]+=wv*t4.y;
          acc[bq*4+2]+=wv*t4.z; acc[bq*4+3]+=wv*t4.w;
        }
      }
    }
  }
  if(tid<vcnt){
    int v=v0+tid;
    float obv=p.ob[v];
#pragma unroll
    for(int b=0;b<40;b++) p.dout[((size_t)(b*T_+t))*V_+v]=acc[b]+obv;
  }
}

// softmax(scc) stats + scatter adds + sel partial
static __device__ void scatsel_ph(const P& p,float* SH,float* red,int t){
  int tid=threadIdx.x,w=tid>>6,lane=tid&63;
  if(blockIdx.x>=240) return;
  int b=blockIdx.x/6, j=blockIdx.x%6;
  int l0=j*167, lcnt=min(167,L_-l0);
  for(int i=tid;i<L_;i+=NTHR) SH[i]=p.scc[b*L_+i];
  __syncthreads();
  float lm=-3.0e38f;
  for(int i=tid;i<L_;i+=NTHR) lm=fmaxf(lm,SH[i]);
  lm=wredMax(lm);
  if(lane==0) red[w]=lm;
  __syncthreads();
  float m=red[0];
#pragma unroll
  for(int q=1;q<8;q++) m=fmaxf(m,red[q]);
  __syncthreads();
  int so=p.inputs[b*T_+t];
  float ls=0.f,lq=0.f;
  for(int i=tid;i<L_;i+=NTHR){
    float exv=expf(SH[i]-m);
    ls+=exv;
    if(p.enc_in[b*L_+i]==so) lq+=exv;
  }
  ls=wredSum(ls); lq=wredSum(lq);
  if(lane==0){red[w]=ls; red[8+w]=lq;}
  __syncthreads();
  float S=0.f,Q=0.f;
#pragma unroll
  for(int q=0;q<8;q++){S+=red[q];Q+=red[8+q];}
  if(tid<lcnt){
    int l=l0+tid;
    float exv=expf(SH[l]-m);
    SH[1024+tid]=(p.enc_in[b*L_+l]==so)?exv:0.f;
    float sc2=p.scale[0]*p.scale[0];
    atomicAdd(p.dout+((size_t)(b*T_+t))*V_+p.enc_in[b*L_+l], exv*sc2/S);
  }
  __syncthreads();
  float inv=1.0f/(Q+1e-8f*S);
  float a=0.f;
  for(int li=0;li<lcnt;li++)
    a+=SH[1024+li]*p.enc[((size_t)(b*L_+l0+li))*H_+tid];
  p.selp[(size_t)(b*6+j)*H_+tid]=a*inv;
}

// per-b argmax over full vocab row (first max wins) -> syms
static __device__ void argmax_ph(const P& p,float* SH,int t){
  int tid=threadIdx.x;
  if(blockIdx.x>=40) return;
  int b=blockIdx.x;
  const float* row=p.dout+((size_t)(b*T_+t))*V_;
  float best=-3.0e38f; int bi=0;
  for(int i4=tid;i4<V_/4;i4+=NTHR){
    float4 x=((const float4*)row)[i4];
    int base=i4*4;
    if(x.x>best){best=x.x;bi=base;}
    if(x.y>best){best=x.y;bi=base+1;}
    if(x.z>best){best=x.z;bi=base+2;}
    if(x.w>best){best=x.w;bi=base+3;}
  }
  int* isa=(int*)(SH+512);
  SH[tid]=best; isa[tid]=bi;
  __syncthreads();
  for(int off=256;off>0;off>>=1){
    if(tid<off){
      float ov=SH[tid+off]; int oi=isa[tid+off];
      if(ov>SH[tid]||(ov==SH[tid]&&oi<isa[tid])){SH[tid]=ov; isa[tid]=oi;}
    }
    __syncthreads();
  }
  if(tid==0) p.dout[(size_t)B_*T_*V_+b*T_+t]=(float)isa[0];
}

__global__ __launch_bounds__(NTHR,2) void k_persist(P p){
  __shared__ float SH[10320];
  __shared__ float gld[512];
  __shared__ float red[16];
  int blk=blockIdx.x, tid=threadIdx.x;
  unsigned bt=0;
#define BARR() do{bt++; gbar(p.cnt,bt*(unsigned)NBLK);}while(0)

  // ===== PREP: M1T/M2T = Wq^T@Wk (transposed), bqk = bq@Wk =====
  {
    int mm=blk>>7, r0=(blk&127)*4;
    const float* Wq = mm? p.a2Wq : p.a1Wq;
    const float* Wk = mm? p.a2Wk : p.a1Wk;
    float* MT = mm? p.M2T : p.M1T;
    float s0=0.f,s1=0.f,s2=0.f,s3=0.f;
    for(int a=0;a<A_;a++){
      float wq=Wq[a*H_+tid];
      s0+=wq*Wk[a*H_+r0+0];
      s1+=wq*Wk[a*H_+r0+1];
      s2+=wq*Wk[a*H_+r0+2];
      s3+=wq*Wk[a*H_+r0+3];
    }
    MT[(size_t)(r0+0)*H_+tid]=s0;
    MT[(size_t)(r0+1)*H_+tid]=s1;
    MT[(size_t)(r0+2)*H_+tid]=s2;
    MT[(size_t)(r0+3)*H_+tid]=s3;
    if((blk&127)==0){
      const float* bq = mm? p.a2bq : p.a1bq;
      float ab=0.f;
      for(int a=0;a<A_;a++) ab+=bq[a]*Wk[a*H_+tid];
      (mm? p.bqk2 : p.bqk1)[tid]=ab;
    }
  }
  // ===== PREP: copyKh = bf16(tanh(enc @ cW^T + cb)), rows padded to 320 =====
  for(int item=blk;item<B_*63;item+=NBLK){
    int b=item/63, lt=item-b*63;
    int l0=lt*16, lcnt=min(16,L_-l0);
    float acc[16];
    float bv=(tid<A_)?p.cb[tid]:0.f;
#pragma unroll
    for(int l=0;l<16;l++) acc[l]=bv;
    for(int k0=0;k0<H_;k0+=32){
      __syncthreads();
      for(int i=tid;i<A_*32;i+=NTHR){
        int a=i>>5,kc=i&31;
        SH[a*33+kc]=p.cW[(size_t)a*H_+k0+kc];
      }
      __syncthreads();
      if(tid<A_){
#pragma unroll
        for(int l=0;l<16;l++){
          if(l<lcnt){
            const float* es=p.enc+((size_t)(b*L_+l0+l))*H_+k0;
            float al=acc[l];
#pragma unroll
            for(int kc=0;kc<32;kc++) al+=SH[tid*33+kc]*es[kc];
            acc[l]=al;
          }
        }
      }
    }
    if(tid<320){
#pragma unroll
      for(int l=0;l<16;l++){
        if(l<lcnt){
          unsigned short hv=0;
          if(tid<A_) hv=f2bf(tanhf(acc[l]));
          p.copyKh[((size_t)(b*L_+l0+l))*320+tid]=hv;
        }
      }
    }
  }
  BARR();

  // ===== decoder steps =====
  for(int t=0;t<T_;t++){
    int rp=t&1, wp=rp^1;
    float* stt=p.stt;
    auto SL=[&](int i,int par){ return stt+((size_t)(i*2+par))*(B_*H_); };
    float *eh1r=SL(0,rp),*eh1w=SL(0,wp),*ec1r=SL(1,rp),*ec1w=SL(1,wp);
    float *eh2r=SL(2,rp),*eh2w=SL(2,wp),*ec2r=SL(3,rp),*ec2w=SL(3,wp);
    float *h1r=SL(4,rp),*h1w=SL(4,wp),*c1r=SL(5,rp),*c1w=SL(5,wp);
    float *h2r=SL(6,rp),*h2w=SL(6,wp),*c2r=SL(7,rp),*c2w=SL(7,wp);

    lstm_ph(p,SH,gld,t,p.e1Wih,E_,p.e1Whh,p.e1b,nullptr,true ,eh1r,ec1r,eh1w,ec1w); BARR();
    lstm_ph(p,SH,gld,t,p.e2Wih,H_,p.e2Whh,p.e2b,eh1w  ,false,eh2r,ec2r,eh2w,ec2w); BARR();

    { // dec_in = concat(emb, eh2, att2_prev, sel_prev) @ in_W^T + in_b + pe
      int w=tid>>6,lane=tid&63;
      int usub=w>>2, kq=w&3;
      int unit=blk*2+usub;
      int rowu=__builtin_amdgcn_readfirstlane(unit);
      float acc=0.f;
      const float* Wr=p.inW+(size_t)rowu*1624;
      const int* inp=p.inputs; const float* emb=p.embed;
      const float* e2=eh2w; const float* a2c=p.att2; const float* sp=p.selp;
      int tt=t;
      gv_accum(SH,1624,Wr,acc,lane,kq,4,[=](int bb,int kk)->float{
        if(kk<E_){int si=(tt==0)?START_:inp[bb*T_+tt-1];return emb[(size_t)si*E_+kk];}
        else if(kk<E_+H_) return e2[bb*H_+kk-E_];
        else if(kk<E_+H_+A_) return a2c[bb*A_+kk-(E_+H_)];
        else{
          int hh=kk-(E_+H_+A_); float s=0.f;
#pragma unroll
          for(int jj=0;jj<6;jj++) s+=sp[(size_t)(bb*6+jj)*H_+hh];
          return s;
        }
      });
      gld[(usub*4+kq)*64+lane]=acc;
      __syncthreads();
      if(w<2&&lane<40){
        int u=blk*2+w;
        float s=gld[(w*4+0)*64+lane]+gld[(w*4+1)*64+lane]
               +gld[(w*4+2)*64+lane]+gld[(w*4+3)*64+lane];
        float ex=(float)(2*(u>>1))/512.0f;
        float ang=(float)t/powf(10000.0f,ex);
        s+=p.inb[u]+((u&1)?cosf(ang):sinf(ang));
        p.dec[lane*H_+u]=s;
      }
      __syncthreads();
    }
    BARR();

    lstm_ph(p,SH,gld,t,p.r1Wih,H_,p.r1Whh,p.r1b,p.dec ,false,h1r,c1r,h1w,c1w); BARR();
    qk_ph(p,SH,h1w,p.M1T,p.bqk1);                                              BARR();
    scctx_ph(p,SH);                                                            BARR();
    atto_ph(p,SH,p.a1Wv,p.a1bv,false);                                         BARR();
    lstm_ph(p,SH,gld,t,p.r2Wih,A_,p.r2Whh,p.r2b,p.att1,false,h2r,c2r,h2w,c2w); BARR();
    qk_ph(p,SH,h2w,p.M2T,p.bqk2);                                              BARR();
    scctx_ph(p,SH);                                                            BARR();
    atto_ph(p,SH,p.a2Wv,p.a2bv,true);                                          BARR();
    copysc_ph(p);                                                              BARR();
    vocab_ph(p,SH,t);                                                          BARR();
    scatsel_ph(p,SH,red,t);                                                    BARR();
    argmax_ph(p,SH,t);
    // no barrier: argmax only touches dout; next phases don't until vocab t+1
  }
#undef BARR
}

extern "C" void kernel_launch(void* const* d_in, const int* in_sizes, int n_in,
                              void* d_out, int out_size, void* d_ws, size_t ws_size,
                              hipStream_t stream){
  P p;
  p.enc_in=(const int*)d_in[0];
  p.enc   =(const float*)d_in[1];
  p.mask  =(const unsigned char*)d_in[2];
  p.inputs=(const int*)d_in[3];
  p.embed =(const float*)d_in[4];
  p.e1Wih=(const float*)d_in[5];  p.e1Whh=(const float*)d_in[6];  p.e1b=(const float*)d_in[7];
  p.e2Wih=(const float*)d_in[8];  p.e2Whh=(const float*)d_in[9];  p.e2b=(const float*)d_in[10];
  p.inW  =(const float*)d_in[11]; p.inb  =(const float*)d_in[12];
  p.r1Wih=(const float*)d_in[13]; p.r1Whh=(const float*)d_in[14]; p.r1b=(const float*)d_in[15];
  p.a1Wq =(const float*)d_in[16]; p.a1bq =(const float*)d_in[17];
  p.a1Wk =(const float*)d_in[18];
  p.a1Wv =(const float*)d_in[20]; p.a1bv =(const float*)d_in[21];
  p.r2Wih=(const float*)d_in[22]; p.r2Whh=(const float*)d_in[23]; p.r2b=(const float*)d_in[24];
  p.a2Wq =(const float*)d_in[25]; p.a2bq =(const float*)d_in[26];
  p.a2Wk =(const float*)d_in[27];
  p.a2Wv =(const float*)d_in[29]; p.a2bv =(const float*)d_in[30];
  p.cW   =(const float*)d_in[31]; p.cb   =(const float*)d_in[32];
  p.oW   =(const float*)d_in[33]; p.ob   =(const float*)d_in[34];
  p.scale=(const float*)d_in[35];
  p.dout=(float*)d_out;

  float* w=(float*)d_ws;
  p.copyKh=(unsigned short*)(w+OFF_CKH);
  p.M1T  =w+OFF_M1T;   p.M2T =w+OFF_M2T;
  p.bqk1 =w+OFF_BQK1;  p.bqk2=w+OFF_BQK2;
  p.qk   =w+OFF_QK;    p.dec =w+OFF_DEC;
  p.att1 =w+OFF_ATT1;  p.attT=w+OFF_ATTT;
  p.cpart=w+OFF_CPART; p.cstat=w+OFF_CSTAT;
  p.scc  =w+OFF_SCC;   p.stt =w+OFF_STT;
  p.att2 =w+OFF_ATT2;  p.selp=w+OFF_SELP;
  p.cnt  =(unsigned*)(w+OFF_CNT);

  // zero: LSTM states (both parities), att2 carry, sel partials, barrier counter
  hipMemsetAsync(w+OFF_STT,0,(WS_END-OFF_STT)*sizeof(float),stream);
  k_persist<<<NBLK,NTHR,0,stream>>>(p);
}

// Round 8
// 17383.595 us; speedup vs baseline: 1.0733x; 1.0733x over previous
//
#include <hip/hip_runtime.h>
#include <math.h>

#define B_ 40
#define L_ 1000
#define H_ 512
#define A_ 300
#define T_ 20
#define E_ 300
#define V_ 78864
#define START_ 2

#define NBLK 256
#define NTHR 512
#define NVT 309            /* ceil(V/256) */

// ---------------- workspace layout (float offsets) ----------------
#define OFF_CKH   0ul          /* bf16 copyK, padded [B][L][320] ushort */
#define OFF_M1T   6400000ul
#define OFF_M2T   6662144ul
#define OFF_BQK1  6924288ul
#define OFF_BQK2  6924800ul
#define OFF_QK    6925312ul
#define OFF_DEC   6945792ul
#define OFF_ATT1  6966272ul
#define OFF_CPART 6978272ul    /* 40*6*512 */
#define OFF_CSTAT 7101152ul    /* 40*6*2 */
#define OFF_ATTA  7101632ul    /* attTall [T][A][B] = 240000 */
#define OFF_SCCA  7341632ul    /* sccAll  [T][B][L] = 800000 */
#define OFF_STT   8141632ul    /* zero region starts here */
#define OFF_ATT2  8469312ul
#define OFF_SELP  8481312ul    /* 40*6*512 */
#define OFF_CNT   8604192ul
#define WS_END    8604256ul

struct P {
  const int* enc_in; const float* enc; const unsigned char* mask; const int* inputs;
  const float* embed;
  const float *e1Wih,*e1Whh,*e1b,*e2Wih,*e2Whh,*e2b;
  const float *inW,*inb;
  const float *r1Wih,*r1Whh,*r1b;
  const float *a1Wq,*a1bq,*a1Wk,*a1Wv,*a1bv;
  const float *r2Wih,*r2Whh,*r2b;
  const float *a2Wq,*a2bq,*a2Wk,*a2Wv,*a2bv;
  const float *cW,*cb,*oW,*ob,*scale;
  float* dout;
  unsigned short* copyKh;
  float *M1T,*M2T,*bqk1,*bqk2,*qk,*dec,*att1,*cpart,*cstat,*attTall,*sccAll,*stt,*att2,*selp;
  unsigned* cnt;
};

__device__ __forceinline__ float sigm(float x){ return 1.0f/(1.0f+expf(-x)); }

__device__ __forceinline__ float wredSum(float v){
#pragma unroll
  for(int o=32;o>0;o>>=1) v+=__shfl_xor(v,o);
  return v;
}
__device__ __forceinline__ float wredMax(float v){
#pragma unroll
  for(int o=32;o>0;o>>=1) v=fmaxf(v,__shfl_xor(v,o));
  return v;
}
__device__ __forceinline__ unsigned short f2bf(float f){
  unsigned u=__float_as_uint(f);
  u=(u+0x7fffu+((u>>16)&1u))>>16;
  return (unsigned short)u;
}

// device-scope grid barrier: monotone counter, memset to 0 before launch
__device__ __forceinline__ void gbar(unsigned* cnt, unsigned target){
  __syncthreads();
  if(threadIdx.x==0){
    __hip_atomic_fetch_add(cnt,1u,__ATOMIC_RELEASE,__HIP_MEMORY_SCOPE_AGENT);
    while(__hip_atomic_load(cnt,__ATOMIC_RELAXED,__HIP_MEMORY_SCOPE_AGENT)<target){
      __builtin_amdgcn_s_sleep(1);
    }
    (void)__hip_atomic_load(cnt,__ATOMIC_ACQUIRE,__HIP_MEMORY_SCOPE_AGENT);
  }
  __syncthreads();
}

// batched-40 GEMV accumulate; xs: LDS [40*257]; lane<40 = batch index.
template<typename SRC>
static __device__ __forceinline__ void gv_accum(float* xs,int K,const float* Wrow,
    float& acc,int lane,int kq,int nq,SRC src){
  for(int k0=0;k0<K;k0+=256){
    int ch=min(256,K-k0);
    __syncthreads();
    if(ch==256){
      float r[20];
#pragma unroll
      for(int u=0;u<20;u++){
        int i=threadIdx.x+u*NTHR;
        r[u]=src(i>>8,k0+(i&255));
      }
#pragma unroll
      for(int u=0;u<20;u++){
        int i=threadIdx.x+u*NTHR;
        xs[(i>>8)*257+(i&255)]=r[u];
      }
    } else {
      for(int i=threadIdx.x;i<40*ch;i+=NTHR){
        int bb=i/ch, kk=i-bb*ch;
        xs[bb*257+kk]=src(bb,k0+kk);
      }
    }
    __syncthreads();
    if(lane<40){
      float a0=0.f,a1=0.f,a2=0.f,a3=0.f;
      int k=kq;
      for(;k+3*nq<ch;k+=4*nq){
        a0+=Wrow[k0+k     ]*xs[lane*257+k];
        a1+=Wrow[k0+k+  nq]*xs[lane*257+k+  nq];
        a2+=Wrow[k0+k+2*nq]*xs[lane*257+k+2*nq];
        a3+=Wrow[k0+k+3*nq]*xs[lane*257+k+3*nq];
      }
      for(;k<ch;k+=nq) a0+=Wrow[k0+k]*xs[lane*257+k];
      acc+=a0+a1+a2+a3;
    }
  }
}

// one LSTM cell for all 40 b: block owns 2 units x 4 gates (8 waves)
static __device__ void lstm_ph(const P& p,float* SH,float* gld,int t,
    const float* Wih,int XD,const float* Whh,const float* bias,
    const float* xvec,bool gather,
    const float* hr,const float* cr,float* hw,float* cw){
  int tid=threadIdx.x,w=tid>>6,lane=tid&63;
  int gate=w&3,usub=w>>2;
  int row=gate*H_+(blockIdx.x*2+usub);
  int rowu=__builtin_amdgcn_readfirstlane(row);
  float acc=bias[rowu];
  const float* W1=Wih+(size_t)rowu*XD;
  if(gather){
    const int* inp=p.inputs; const float* emb=p.embed; int tt=t;
    gv_accum(SH,XD,W1,acc,lane,0,1,[=](int bb,int kk)->float{
      int si=(tt==0)?START_:inp[bb*T_+tt-1];
      return emb[(size_t)si*E_+kk];});
  }else{
    gv_accum(SH,XD,W1,acc,lane,0,1,[=](int bb,int kk)->float{
      return xvec[(size_t)bb*XD+kk];});
  }
  const float* W2=Whh+(size_t)rowu*H_;
  gv_accum(SH,H_,W2,acc,lane,0,1,[=](int bb,int kk)->float{
    return hr[bb*H_+kk];});
  gld[w*64+lane]=acc;
  __syncthreads();
  if(w<2&&lane<40){
    int u=blockIdx.x*2+w,b=lane;
    float gi=gld[(w*4+0)*64+b],gf=gld[(w*4+1)*64+b],gg=gld[(w*4+2)*64+b],go=gld[(w*4+3)*64+b];
    float c=cr[b*H_+u];
    float cn=sigm(gf)*c+sigm(gi)*tanhf(gg);
    hw[b*H_+u]=sigm(go)*tanhf(cn);
    cw[b*H_+u]=cn;
  }
  __syncthreads();
}

// qk[b][h'] = bqk[h'] + sum_h hsrc[b][h] * MT[h'][h]
static __device__ void qk_ph(const P& p,float* SH,const float* hsrc,
    const float* MT,const float* bqk){
  int tid=threadIdx.x;
  if(blockIdx.x>=240) return;
  int b=blockIdx.x/6, j=blockIdx.x%6;
  SH[tid]=hsrc[b*H_+tid];
  __syncthreads();
  int h0=j*86, hc=min(86,H_-h0);
  if(tid<hc){
    int hp=h0+tid;
    float a=bqk[hp];
    const float4* mr=(const float4*)(MT+(size_t)hp*H_);
#pragma unroll 8
    for(int i=0;i<H_/4;i++){
      float4 m4=mr[i];
      a+=SH[4*i]*m4.x+SH[4*i+1]*m4.y+SH[4*i+2]*m4.z+SH[4*i+3]*m4.w;
    }
    p.qk[b*H_+hp]=a;
  }
}

// fused scores + online-softmax ctx partial; 16-row tiles with register prefetch
static __device__ void scctx_ph(const P& p,float* SH){
  int tid=threadIdx.x,w=tid>>6,lane=tid&63;
  if(blockIdx.x>=240) return;
  int b=blockIdx.x/6, j=blockIdx.x%6;
  int l0=j*167, lcnt=min(167,L_-l0);
  const float* qrow=p.qk+b*H_;
  float4 q0=*(const float4*)(qrow+lane*8);
  float4 q1=*(const float4*)(qrow+lane*8+4);
  float* tile=SH;            // [16*512]
  float* sc16=SH+8192;       // [16]
  const float4* base=(const float4*)(p.enc+((size_t)(b*L_+l0))*H_);
  float4 pre[4];
  { int rem=lcnt*128;
#pragma unroll
    for(int u=0;u<4;u++){ int i=tid+u*NTHR; pre[u]=(i<rem)?base[i]:make_float4(0.f,0.f,0.f,0.f); } }
  float m=-3.0e38f,S=0.f,acc=0.f;
  for(int t0=0;t0<lcnt;t0+=16){
    int tc=min(16,lcnt-t0);
    __syncthreads();
    { float4* dst=(float4*)tile;
#pragma unroll
      for(int u=0;u<4;u++){ int i=tid+u*NTHR; if(i<tc*128) dst[i]=pre[u]; } }
    __syncthreads();
    if(t0+16<lcnt){                     // issue next tile's loads (hidden under compute)
      int rem=(lcnt-t0-16)*128;
      const float4* src=base+(size_t)(t0+16)*128;
#pragma unroll
      for(int u=0;u<4;u++){ int i=tid+u*NTHR; pre[u]=(i<rem)?src[i]:make_float4(0.f,0.f,0.f,0.f); }
    }
#pragma unroll
    for(int r=0;r<2;r++){
      int row=w*2+r;
      float sc=-1e30f;
      if(row<tc){
        const float4* er=(const float4*)(tile+row*512);
        float4 e0=er[lane*2], e1=er[lane*2+1];
        float pp=q0.x*e0.x+q0.y*e0.y+q0.z*e0.z+q0.w*e0.w
                +q1.x*e1.x+q1.y*e1.y+q1.z*e1.z+q1.w*e1.w;
        pp=wredSum(pp);
        sc=p.mask[b*L_+l0+t0+row]?-1e9f:pp;
      }
      if(lane==0) sc16[row]=sc;
    }
    __syncthreads();
    float tm=-3.0e38f;
    for(int r=0;r<tc;r++) tm=fmaxf(tm,sc16[r]);
    float mn=fmaxf(m,tm);
    float scl=expf(m-mn);
    float Sadd=0.f, aadd=0.f;
    for(int r=0;r<tc;r++){
      float pe=expf(sc16[r]-mn);
      Sadd+=pe;
      aadd+=pe*tile[r*512+tid];
    }
    S=S*scl+Sadd;
    acc=acc*scl+aadd;
    m=mn;
  }
  p.cpart[(size_t)(b*6+j)*H_+tid]=acc;
  if(tid==0){p.cstat[(b*6+j)*2]=m; p.cstat[(b*6+j)*2+1]=S;}
}

// combine 6 ctx partials, project through Wv (+bv) -> att; ADD also stores attTall[t]
static __device__ void atto_ph(const P& p,float* SH,const float* Wv,const float* bv,
    bool ADD,int t){
  int tid=threadIdx.x;
  if(blockIdx.x>=40) return;
  int b=blockIdx.x;
  float mb=-3.0e38f;
#pragma unroll
  for(int j=0;j<6;j++) mb=fmaxf(mb,p.cstat[(b*6+j)*2]);
  float Sb=0.f;
#pragma unroll
  for(int j=0;j<6;j++) Sb+=p.cstat[(b*6+j)*2+1]*expf(p.cstat[(b*6+j)*2]-mb);
  float inv=1.0f/Sb;
  float cx=0.f;
#pragma unroll
  for(int j=0;j<6;j++) cx+=expf(p.cstat[(b*6+j)*2]-mb)*p.cpart[(size_t)(b*6+j)*H_+tid];
  SH[tid]=cx*inv;
  __syncthreads();
  if(tid<A_){
    float a=bv[tid];
    const float4* wr=(const float4*)(Wv+(size_t)tid*H_);
#pragma unroll 8
    for(int i=0;i<H_/4;i++){
      float4 w4=wr[i];
      a+=SH[4*i]*w4.x+SH[4*i+1]*w4.y+SH[4*i+2]*w4.z+SH[4*i+3]*w4.w;
    }
    if(ADD){
      a+=p.att1[b*A_+tid];
      p.att2[b*A_+tid]=a;
      p.attTall[(size_t)t*A_*B_+tid*B_+b]=a;
    }
    else p.att1[b*A_+tid]=a;
  }
}

// copy scores from bf16 copyK (16B/lane) -> sccAll[t]
static __device__ void copysc_ph(const P& p,int t){
  int tid=threadIdx.x,w=tid>>6,lane=tid&63;
  if(blockIdx.x>=240) return;
  int b=blockIdx.x/6, j=blockIdx.x%6;
  int l0=j*167, lcnt=min(167,L_-l0);
  float* scct=p.sccAll+(size_t)t*B_*L_;
  float ar[8];
#pragma unroll
  for(int q=0;q<8;q++){
    int a=lane*8+q;
    ar[q]=(lane<40&&a<A_)? p.att2[b*A_+a] : 0.f;
  }
  for(int l=l0+w;l<l0+lcnt;l+=8){
    float pp=0.f;
    if(lane<40){
      const uint4* cr=(const uint4*)(p.copyKh+((size_t)(b*L_+l))*320);
      uint4 kk=cr[lane];
      pp =ar[0]*__uint_as_float(kk.x<<16)+ar[1]*__uint_as_float(kk.x&0xffff0000u);
      pp+=ar[2]*__uint_as_float(kk.y<<16)+ar[3]*__uint_as_float(kk.y&0xffff0000u);
      pp+=ar[4]*__uint_as_float(kk.z<<16)+ar[5]*__uint_as_float(kk.z&0xffff0000u);
      pp+=ar[6]*__uint_as_float(kk.w<<16)+ar[7]*__uint_as_float(kk.w&0xffff0000u);
    }
    pp=wredSum(pp);
    if(lane==0) scct[b*L_+l]=p.mask[b*L_+l]?-1e9f:pp;
  }
}

// softmax(sccAll[t]) stats + sel partial only (scatter deferred)
static __device__ void sel_ph(const P& p,float* SH,float* red,int t){
  int tid=threadIdx.x,w=tid>>6,lane=tid&63;
  if(blockIdx.x>=240) return;
  int b=blockIdx.x/6, j=blockIdx.x%6;
  int l0=j*167, lcnt=min(167,L_-l0);
  const float* scct=p.sccAll+(size_t)t*B_*L_;
  for(int i=tid;i<L_;i+=NTHR) SH[i]=scct[b*L_+i];
  __syncthreads();
  float lm=-3.0e38f;
  for(int i=tid;i<L_;i+=NTHR) lm=fmaxf(lm,SH[i]);
  lm=wredMax(lm);
  if(lane==0) red[w]=lm;
  __syncthreads();
  float m=red[0];
#pragma unroll
  for(int q=1;q<8;q++) m=fmaxf(m,red[q]);
  __syncthreads();
  int so=p.inputs[b*T_+t];
  float ls=0.f,lq=0.f;
  for(int i=tid;i<L_;i+=NTHR){
    float exv=expf(SH[i]-m);
    ls+=exv;
    if(p.enc_in[b*L_+i]==so) lq+=exv;
  }
  ls=wredSum(ls); lq=wredSum(lq);
  if(lane==0){red[w]=ls; red[8+w]=lq;}
  __syncthreads();
  float S=0.f,Q=0.f;
#pragma unroll
  for(int q=0;q<8;q++){S+=red[q];Q+=red[8+q];}
  if(tid<lcnt){
    int l=l0+tid;
    float exv=expf(SH[l]-m);
    SH[1024+tid]=(p.enc_in[b*L_+l]==so)?exv:0.f;
  }
  __syncthreads();
  // sel partial: thread = (rg 0..3, h4 0..127); float4 along h
  int h4=tid&127, rg=tid>>7;
  float4 a4=make_float4(0.f,0.f,0.f,0.f);
#pragma unroll 2
  for(int li=rg;li<lcnt;li+=4){
    float wgt=SH[1024+li];
    float4 ev=*(const float4*)(p.enc+((size_t)(b*L_+l0+li))*H_+h4*4);
    a4.x+=wgt*ev.x; a4.y+=wgt*ev.y; a4.z+=wgt*ev.z; a4.w+=wgt*ev.w;
  }
  *(float4*)(SH+2048+tid*4)=a4;
  __syncthreads();
  float inv=1.0f/(Q+1e-8f*S);
  float s=SH[2048+tid]+SH[2048+512+tid]+SH[2048+1024+tid]+SH[2048+1536+tid];
  p.selp[(size_t)(b*6+j)*H_+tid]=s*inv;
}

__global__ __launch_bounds__(NTHR,2) void k_persist(P p){
  __shared__ float SH[10560];
  __shared__ float gld[512];
  __shared__ float red[16];
  int blk=blockIdx.x, tid=threadIdx.x;
  unsigned bt=0;
#define BARR() do{bt++; gbar(p.cnt,bt*(unsigned)NBLK);}while(0)

  // ===== PREP: M1T/M2T = Wq^T@Wk (transposed), bqk = bq@Wk =====
  {
    int mm=blk>>7, r0=(blk&127)*4;
    const float* Wq = mm? p.a2Wq : p.a1Wq;
    const float* Wk = mm? p.a2Wk : p.a1Wk;
    float* MT = mm? p.M2T : p.M1T;
    float s0=0.f,s1=0.f,s2=0.f,s3=0.f;
    for(int a=0;a<A_;a++){
      float wq=Wq[a*H_+tid];
      s0+=wq*Wk[a*H_+r0+0];
      s1+=wq*Wk[a*H_+r0+1];
      s2+=wq*Wk[a*H_+r0+2];
      s3+=wq*Wk[a*H_+r0+3];
    }
    MT[(size_t)(r0+0)*H_+tid]=s0;
    MT[(size_t)(r0+1)*H_+tid]=s1;
    MT[(size_t)(r0+2)*H_+tid]=s2;
    MT[(size_t)(r0+3)*H_+tid]=s3;
    if((blk&127)==0){
      const float* bq = mm? p.a2bq : p.a1bq;
      float ab=0.f;
      for(int a=0;a<A_;a++) ab+=bq[a]*Wk[a*H_+tid];
      (mm? p.bqk2 : p.bqk1)[tid]=ab;
    }
  }
  // ===== PREP: copyKh = bf16(tanh(enc @ cW^T + cb)), rows padded to 320 =====
  for(int item=blk;item<B_*63;item+=NBLK){
    int b=item/63, lt=item-b*63;
    int l0=lt*16, lcnt=min(16,L_-l0);
    float acc[16];
    float bv=(tid<A_)?p.cb[tid]:0.f;
#pragma unroll
    for(int l=0;l<16;l++) acc[l]=bv;
    for(int k0=0;k0<H_;k0+=32){
      __syncthreads();
      for(int i=tid;i<A_*32;i+=NTHR){
        int a=i>>5,kc=i&31;
        SH[a*33+kc]=p.cW[(size_t)a*H_+k0+kc];
      }
      __syncthreads();
      if(tid<A_){
#pragma unroll
        for(int l=0;l<16;l++){
          if(l<lcnt){
            const float* es=p.enc+((size_t)(b*L_+l0+l))*H_+k0;
            float al=acc[l];
#pragma unroll
            for(int kc=0;kc<32;kc++) al+=SH[tid*33+kc]*es[kc];
            acc[l]=al;
          }
        }
      }
    }
    if(tid<320){
#pragma unroll
      for(int l=0;l<16;l++){
        if(l<lcnt){
          unsigned short hv=0;
          if(tid<A_) hv=f2bf(tanhf(acc[l]));
          p.copyKh[((size_t)(b*L_+l0+l))*320+tid]=hv;
        }
      }
    }
  }
  BARR();

  // ===== recurrent decoder steps (no vocab/scatter/argmax) =====
  for(int t=0;t<T_;t++){
    int rp=t&1, wp=rp^1;
    float* stt=p.stt;
    auto SL=[&](int i,int par){ return stt+((size_t)(i*2+par))*(B_*H_); };
    float *eh1r=SL(0,rp),*eh1w=SL(0,wp),*ec1r=SL(1,rp),*ec1w=SL(1,wp);
    float *eh2r=SL(2,rp),*eh2w=SL(2,wp),*ec2r=SL(3,rp),*ec2w=SL(3,wp);
    float *h1r=SL(4,rp),*h1w=SL(4,wp),*c1r=SL(5,rp),*c1w=SL(5,wp);
    float *h2r=SL(6,rp),*h2w=SL(6,wp),*c2r=SL(7,rp),*c2w=SL(7,wp);

    lstm_ph(p,SH,gld,t,p.e1Wih,E_,p.e1Whh,p.e1b,nullptr,true ,eh1r,ec1r,eh1w,ec1w); BARR();
    lstm_ph(p,SH,gld,t,p.e2Wih,H_,p.e2Whh,p.e2b,eh1w  ,false,eh2r,ec2r,eh2w,ec2w); BARR();

    { // dec_in = concat(emb, eh2, att2_prev, sel_prev) @ in_W^T + in_b + pe
      int w=tid>>6,lane=tid&63;
      int usub=w>>2, kq=w&3;
      int unit=blk*2+usub;
      int rowu=__builtin_amdgcn_readfirstlane(unit);
      float acc=0.f;
      const float* Wr=p.inW+(size_t)rowu*1624;
      const int* inp=p.inputs; const float* emb=p.embed;
      const float* e2=eh2w; const float* a2c=p.att2; const float* sp=p.selp;
      int tt=t;
      gv_accum(SH,1624,Wr,acc,lane,kq,4,[=](int bb,int kk)->float{
        if(kk<E_){int si=(tt==0)?START_:inp[bb*T_+tt-1];return emb[(size_t)si*E_+kk];}
        else if(kk<E_+H_) return e2[bb*H_+kk-E_];
        else if(kk<E_+H_+A_) return a2c[bb*A_+kk-(E_+H_)];
        else{
          int hh=kk-(E_+H_+A_); float s=0.f;
#pragma unroll
          for(int jj=0;jj<6;jj++) s+=sp[(size_t)(bb*6+jj)*H_+hh];
          return s;
        }
      });
      gld[(usub*4+kq)*64+lane]=acc;
      __syncthreads();
      if(w<2&&lane<40){
        int u=blk*2+w;
        float s=gld[(w*4+0)*64+lane]+gld[(w*4+1)*64+lane]
               +gld[(w*4+2)*64+lane]+gld[(w*4+3)*64+lane];
        float ex=(float)(2*(u>>1))/512.0f;
        float ang=(float)t/powf(10000.0f,ex);
        s+=p.inb[u]+((u&1)?cosf(ang):sinf(ang));
        p.dec[lane*H_+u]=s;
      }
      __syncthreads();
    }
    BARR();

    lstm_ph(p,SH,gld,t,p.r1Wih,H_,p.r1Whh,p.r1b,p.dec ,false,h1r,c1r,h1w,c1w); BARR();
    qk_ph(p,SH,h1w,p.M1T,p.bqk1);                                              BARR();
    scctx_ph(p,SH);                                                            BARR();
    atto_ph(p,SH,p.a1Wv,p.a1bv,false,t);                                       BARR();
    lstm_ph(p,SH,gld,t,p.r2Wih,A_,p.r2Whh,p.r2b,p.att1,false,h2r,c2r,h2w,c2w); BARR();
    qk_ph(p,SH,h2w,p.M2T,p.bqk2);                                              BARR();
    scctx_ph(p,SH);                                                            BARR();
    atto_ph(p,SH,p.a2Wv,p.a2bv,true,t);                                        BARR();
    copysc_ph(p,t);                                                            BARR();
    sel_ph(p,SH,red,t);                                                        BARR();
  }

  // ===== FINAL A: vocab logits for ALL t, balanced (v-tile, t) items =====
  {
    int row=tid>>1, half=tid&1;
    for(int item=blk;item<NVT*T_;item+=NBLK){
      int vt=item/T_, t=item-vt*T_;
      long v0=(long)vt*256;
      int vcnt=min(256,(int)(V_-v0));
      float acc[20];
#pragma unroll
      for(int q=0;q<20;q++) acc[q]=0.f;
      for(int c=0;c<10;c++){
        int a0=c*32, aw=min(32,A_-a0);
        __syncthreads();
        if(c<9){
          int tot=vcnt*8;
          for(int i=tid;i<tot;i+=NTHR){
            int vr=i>>3, f=i&7;
            *(float4*)&SH[vr*36+f*4]=*(const float4*)(p.oW+(size_t)(v0+vr)*A_+a0+f*4);
          }
          for(int i=tid;i<32*40;i+=NTHR) SH[9216+i]=p.attTall[(size_t)t*A_*B_+a0*B_+i];
        } else {
          int tot=vcnt*3;
          for(int i=tid;i<tot;i+=NTHR){
            int vr=i/3, f=i-vr*3;
            *(float4*)&SH[vr*36+f*4]=*(const float4*)(p.oW+(size_t)(v0+vr)*A_+a0+f*4);
          }
          for(int i=tid;i<12*40;i+=NTHR) SH[9216+i]=p.attTall[(size_t)t*A_*B_+a0*B_+i];
        }
        __syncthreads();
        if(row<vcnt){
          const float* wrow=&SH[row*36];
          for(int ac=0;ac<aw;ac++){
            float wv=wrow[ac];
            const float* at=&SH[9216+ac*40+half*20];
#pragma unroll
            for(int bq=0;bq<5;bq++){
              float4 t4=*(const float4*)(at+bq*4);
              acc[bq*4+0]+=wv*t4.x; acc[bq*4+1]+=wv*t4.y;
              acc[bq*4+2]+=wv*t4.z; acc[bq*4+3]+=wv*t4.w;
            }
          }
        }
      }
      if(row<vcnt){
        long v=v0+row;
        float obv=p.ob[v];
#pragma unroll
        for(int bb=0;bb<20;bb++){
          int b=half*20+bb;
          p.dout[((size_t)(b*T_+t))*V_+v]=acc[bb]+obv;
        }
      }
    }
  }
  BARR();

  // ===== FINAL B: deferred scatter adds =====
  {
    int w=tid>>6,lane=tid&63;
    float sc2=p.scale[0]*p.scale[0];
    for(int it=blk;it<B_*T_;it+=NBLK){
      int b=it/T_, t=it-b*T_;
      const float* scr=p.sccAll+((size_t)t*B_+b)*L_;
      __syncthreads();
      for(int i=tid;i<L_;i+=NTHR) SH[i]=scr[i];
      __syncthreads();
      float lm=-3.0e38f;
      for(int i=tid;i<L_;i+=NTHR) lm=fmaxf(lm,SH[i]);
      lm=wredMax(lm);
      if(lane==0) red[w]=lm;
      __syncthreads();
      float m=red[0];
#pragma unroll
      for(int q=1;q<8;q++) m=fmaxf(m,red[q]);
      __syncthreads();
      float ls=0.f;
      for(int i=tid;i<L_;i+=NTHR) ls+=expf(SH[i]-m);
      ls=wredSum(ls);
      if(lane==0) red[w]=ls;
      __syncthreads();
      float S=0.f;
#pragma unroll
      for(int q=0;q<8;q++) S+=red[q];
      float f=sc2/S;
      float* drow=p.dout+((size_t)(b*T_+t))*V_;
      const int* ei=p.enc_in+b*L_;
      for(int i=tid;i<L_;i+=NTHR) atomicAdd(drow+ei[i], expf(SH[i]-m)*f);
      __syncthreads();
    }
  }
  BARR();

  // ===== FINAL C: argmax per (b,t) row -> syms =====
  {
    int* isa=(int*)(SH+512);
    for(int it=blk;it<B_*T_;it+=NBLK){
      int b=it/T_, t=it-b*T_;
      const float* row=p.dout+((size_t)(b*T_+t))*V_;
      float best=-3.0e38f; int bi=0;
      for(int i4=tid;i4<V_/4;i4+=NTHR){
        float4 x=((const float4*)row)[i4];
        int base=i4*4;
        if(x.x>best){best=x.x;bi=base;}
        if(x.y>best){best=x.y;bi=base+1;}
        if(x.z>best){best=x.z;bi=base+2;}
        if(x.w>best){best=x.w;bi=base+3;}
      }
      __syncthreads();
      SH[tid]=best; isa[tid]=bi;
      __syncthreads();
      for(int off=256;off>0;off>>=1){
        if(tid<off){
          float ov=SH[tid+off]; int oi=isa[tid+off];
          if(ov>SH[tid]||(ov==SH[tid]&&oi<isa[tid])){SH[tid]=ov; isa[tid]=oi;}
        }
        __syncthreads();
      }
      if(tid==0) p.dout[(size_t)B_*T_*V_+b*T_+t]=(float)isa[0];
    }
  }
#undef BARR
}

extern "C" void kernel_launch(void* const* d_in, const int* in_sizes, int n_in,
                              void* d_out, int out_size, void* d_ws, size_t ws_size,
                              hipStream_t stream){
  P p;
  p.enc_in=(const int*)d_in[0];
  p.enc   =(const float*)d_in[1];
  p.mask  =(const unsigned char*)d_in[2];
  p.inputs=(const int*)d_in[3];
  p.embed =(const float*)d_in[4];
  p.e1Wih=(const float*)d_in[5];  p.e1Whh=(const float*)d_in[6];  p.e1b=(const float*)d_in[7];
  p.e2Wih=(const float*)d_in[8];  p.e2Whh=(const float*)d_in[9];  p.e2b=(const float*)d_in[10];
  p.inW  =(const float*)d_in[11]; p.inb  =(const float*)d_in[12];
  p.r1Wih=(const float*)d_in[13]; p.r1Whh=(const float*)d_in[14]; p.r1b=(const float*)d_in[15];
  p.a1Wq =(const float*)d_in[16]; p.a1bq =(const float*)d_in[17];
  p.a1Wk =(const float*)d_in[18];
  p.a1Wv =(const float*)d_in[20]; p.a1bv =(const float*)d_in[21];
  p.r2Wih=(const float*)d_in[22]; p.r2Whh=(const float*)d_in[23]; p.r2b=(const float*)d_in[24];
  p.a2Wq =(const float*)d_in[25]; p.a2bq =(const float*)d_in[26];
  p.a2Wk =(const float*)d_in[27];
  p.a2Wv =(const float*)d_in[29]; p.a2bv =(const float*)d_in[30];
  p.cW   =(const float*)d_in[31]; p.cb   =(const float*)d_in[32];
  p.oW   =(const float*)d_in[33]; p.ob   =(const float*)d_in[34];
  p.scale=(const float*)d_in[35];
  p.dout=(float*)d_out;

  float* w=(float*)d_ws;
  p.copyKh=(unsigned short*)(w+OFF_CKH);
  p.M1T  =w+OFF_M1T;    p.M2T =w+OFF_M2T;
  p.bqk1 =w+OFF_BQK1;   p.bqk2=w+OFF_BQK2;
  p.qk   =w+OFF_QK;     p.dec =w+OFF_DEC;
  p.att1 =w+OFF_ATT1;
  p.cpart=w+OFF_CPART;  p.cstat=w+OFF_CSTAT;
  p.attTall=w+OFF_ATTA; p.sccAll=w+OFF_SCCA;
  p.stt  =w+OFF_STT;
  p.att2 =w+OFF_ATT2;   p.selp=w+OFF_SELP;
  p.cnt  =(unsigned*)(w+OFF_CNT);

  // zero: LSTM states (both parities), att2 carry, sel partials, barrier counter
  hipMemsetAsync(w+OFF_STT,0,(WS_END-OFF_STT)*sizeof(float),stream);
  k_persist<<<NBLK,NTHR,0,stream>>>(p);
}

// Round 9
// 16090.550 us; speedup vs baseline: 1.1596x; 1.0804x over previous
//
#include <hip/hip_runtime.h>
#include <math.h>

#define B_ 40
#define L_ 1000
#define H_ 512
#define A_ 300
#define T_ 20
#define E_ 300
#define V_ 78864
#define START_ 2

#define NBLK 256
#define NTHR 512
#define NVT 309            /* ceil(V/256) */

// ---------------- workspace layout (float offsets) ----------------
#define OFF_CKH   0ul          /* bf16 copyK, padded [B][L][320] ushort */
#define OFF_M1T   6400000ul
#define OFF_M2T   6662144ul
#define OFF_BQK1  6924288ul
#define OFF_BQK2  6924800ul
#define OFF_QK    6925312ul
#define OFF_DEC   6945792ul
#define OFF_ATT1  6966272ul
#define OFF_CPART 6978272ul    /* 40*6*512 */
#define OFF_CSTAT 7101152ul    /* 40*6*2 */
#define OFF_ATTA  7101632ul    /* attTall [T][A][B] = 240000 */
#define OFF_SCCA  7341632ul    /* sccAll  [T][B][L] = 800000 */
#define OFF_STT   8141632ul    /* zero region starts here */
#define OFF_ATT2  8469312ul
#define OFF_SELP  8481312ul    /* 40*6*512 */
#define OFF_FLAGS 8604192ul    /* 256 flags at 32-uint (128B) stride */
#define OFF_REL   8612384ul
#define WS_END    8612448ul

struct P {
  const int* enc_in; const float* enc; const unsigned char* mask; const int* inputs;
  const float* embed;
  const float *e1Wih,*e1Whh,*e1b,*e2Wih,*e2Whh,*e2b;
  const float *inW,*inb;
  const float *r1Wih,*r1Whh,*r1b;
  const float *a1Wq,*a1bq,*a1Wk,*a1Wv,*a1bv;
  const float *r2Wih,*r2Whh,*r2b;
  const float *a2Wq,*a2bq,*a2Wk,*a2Wv,*a2bv;
  const float *cW,*cb,*oW,*ob,*scale;
  float* dout;
  unsigned short* copyKh;
  float *M1T,*M2T,*bqk1,*bqk2,*qk,*dec,*att1,*cpart,*cstat,*attTall,*sccAll,*stt,*att2,*selp;
  unsigned *flags,*rel;
};

__device__ __forceinline__ float sigm(float x){ return 1.0f/(1.0f+expf(-x)); }

__device__ __forceinline__ float wredSum(float v){
#pragma unroll
  for(int o=32;o>0;o>>=1) v+=__shfl_xor(v,o);
  return v;
}
__device__ __forceinline__ float wredMax(float v){
#pragma unroll
  for(int o=32;o>0;o>>=1) v=fmaxf(v,__shfl_xor(v,o));
  return v;
}
__device__ __forceinline__ unsigned short f2bf(float f){
  unsigned u=__float_as_uint(f);
  u=(u+0x7fffu+((u>>16)&1u))>>16;
  return (unsigned short)u;
}

// flag/coordinator grid barrier: per-block flags on separate cache lines
// (stores, no RMW contention), block 0 aggregates and broadcasts a release
// word. Epochs are monotone; flags/rel memset to 0 each launch.
__device__ __forceinline__ void gbar2(unsigned* flags, unsigned* rel, unsigned epoch){
  __syncthreads();
  int tid=threadIdx.x;
  if(blockIdx.x==0){
    if(tid>0 && tid<NBLK){
      while(__hip_atomic_load(flags+(unsigned)tid*32u,__ATOMIC_RELAXED,__HIP_MEMORY_SCOPE_AGENT)<epoch)
        __builtin_amdgcn_s_sleep(2);
      (void)__hip_atomic_load(flags+(unsigned)tid*32u,__ATOMIC_ACQUIRE,__HIP_MEMORY_SCOPE_AGENT);
    }
    __syncthreads();
    if(tid==0)
      __hip_atomic_store(rel,epoch,__ATOMIC_RELEASE,__HIP_MEMORY_SCOPE_AGENT);
  } else {
    if(tid==0){
      __hip_atomic_store(flags+(unsigned)blockIdx.x*32u,epoch,__ATOMIC_RELEASE,__HIP_MEMORY_SCOPE_AGENT);
      while(__hip_atomic_load(rel,__ATOMIC_RELAXED,__HIP_MEMORY_SCOPE_AGENT)<epoch)
        __builtin_amdgcn_s_sleep(2);
      (void)__hip_atomic_load(rel,__ATOMIC_ACQUIRE,__HIP_MEMORY_SCOPE_AGENT);
    }
    __syncthreads();
  }
}

// batched-40 GEMV accumulate; xs: LDS [40*257]; lane<40 = batch index.
template<typename SRC>
static __device__ __forceinline__ void gv_accum(float* xs,int K,const float* Wrow,
    float& acc,int lane,int kq,int nq,SRC src){
  for(int k0=0;k0<K;k0+=256){
    int ch=min(256,K-k0);
    __syncthreads();
    if(ch==256){
      float r[20];
#pragma unroll
      for(int u=0;u<20;u++){
        int i=threadIdx.x+u*NTHR;
        r[u]=src(i>>8,k0+(i&255));
      }
#pragma unroll
      for(int u=0;u<20;u++){
        int i=threadIdx.x+u*NTHR;
        xs[(i>>8)*257+(i&255)]=r[u];
      }
    } else {
      for(int i=threadIdx.x;i<40*ch;i+=NTHR){
        int bb=i/ch, kk=i-bb*ch;
        xs[bb*257+kk]=src(bb,k0+kk);
      }
    }
    __syncthreads();
    if(lane<40){
      float a0=0.f,a1=0.f,a2=0.f,a3=0.f;
      int k=kq;
      for(;k+3*nq<ch;k+=4*nq){
        a0+=Wrow[k0+k     ]*xs[lane*257+k];
        a1+=Wrow[k0+k+  nq]*xs[lane*257+k+  nq];
        a2+=Wrow[k0+k+2*nq]*xs[lane*257+k+2*nq];
        a3+=Wrow[k0+k+3*nq]*xs[lane*257+k+3*nq];
      }
      for(;k<ch;k+=nq) a0+=Wrow[k0+k]*xs[lane*257+k];
      acc+=a0+a1+a2+a3;
    }
  }
}

// one LSTM cell for all 40 b: block owns 2 units x 4 gates (8 waves)
static __device__ void lstm_ph(const P& p,float* SH,float* gld,int t,
    const float* Wih,int XD,const float* Whh,const float* bias,
    const float* xvec,bool gather,
    const float* hr,const float* cr,float* hw,float* cw){
  int tid=threadIdx.x,w=tid>>6,lane=tid&63;
  int gate=w&3,usub=w>>2;
  int row=gate*H_+(blockIdx.x*2+usub);
  int rowu=__builtin_amdgcn_readfirstlane(row);
  float acc=bias[rowu];
  const float* W1=Wih+(size_t)rowu*XD;
  if(gather){
    const int* inp=p.inputs; const float* emb=p.embed; int tt=t;
    gv_accum(SH,XD,W1,acc,lane,0,1,[=](int bb,int kk)->float{
      int si=(tt==0)?START_:inp[bb*T_+tt-1];
      return emb[(size_t)si*E_+kk];});
  }else{
    gv_accum(SH,XD,W1,acc,lane,0,1,[=](int bb,int kk)->float{
      return xvec[(size_t)bb*XD+kk];});
  }
  const float* W2=Whh+(size_t)rowu*H_;
  gv_accum(SH,H_,W2,acc,lane,0,1,[=](int bb,int kk)->float{
    return hr[bb*H_+kk];});
  gld[w*64+lane]=acc;
  __syncthreads();
  if(w<2&&lane<40){
    int u=blockIdx.x*2+w,b=lane;
    float gi=gld[(w*4+0)*64+b],gf=gld[(w*4+1)*64+b],gg=gld[(w*4+2)*64+b],go=gld[(w*4+3)*64+b];
    float c=cr[b*H_+u];
    float cn=sigm(gf)*c+sigm(gi)*tanhf(gg);
    hw[b*H_+u]=sigm(go)*tanhf(cn);
    cw[b*H_+u]=cn;
  }
  __syncthreads();
}

// qk[b][h'] = bqk[h'] + sum_h hsrc[b][h] * MT[h'][h]
static __device__ void qk_ph(const P& p,float* SH,const float* hsrc,
    const float* MT,const float* bqk){
  int tid=threadIdx.x;
  if(blockIdx.x>=240) return;
  int b=blockIdx.x/6, j=blockIdx.x%6;
  SH[tid]=hsrc[b*H_+tid];
  __syncthreads();
  int h0=j*86, hc=min(86,H_-h0);
  if(tid<hc){
    int hp=h0+tid;
    float a=bqk[hp];
    const float4* mr=(const float4*)(MT+(size_t)hp*H_);
#pragma unroll 8
    for(int i=0;i<H_/4;i++){
      float4 m4=mr[i];
      a+=SH[4*i]*m4.x+SH[4*i+1]*m4.y+SH[4*i+2]*m4.z+SH[4*i+3]*m4.w;
    }
    p.qk[b*H_+hp]=a;
  }
}

// fused scores + online-softmax ctx partial; 24-row tiles with register prefetch
static __device__ void scctx_ph(const P& p,float* SH){
  int tid=threadIdx.x,w=tid>>6,lane=tid&63;
  if(blockIdx.x>=240) return;
  int b=blockIdx.x/6, j=blockIdx.x%6;
  int l0=j*167, lcnt=min(167,L_-l0);
  const float* qrow=p.qk+b*H_;
  float4 q0=*(const float4*)(qrow+lane*8);
  float4 q1=*(const float4*)(qrow+lane*8+4);
  float* tile=SH;            // [24*512]
  float* sc24=SH+12288;      // [24]
  const float4* base=(const float4*)(p.enc+((size_t)(b*L_+l0))*H_);
  float4 pre[6];
  { int rem=lcnt*128;
#pragma unroll
    for(int u=0;u<6;u++){ int i=tid+u*NTHR; pre[u]=(i<rem)?base[i]:make_float4(0.f,0.f,0.f,0.f); } }
  float m=-3.0e38f,S=0.f,acc=0.f;
  for(int t0=0;t0<lcnt;t0+=24){
    int tc=min(24,lcnt-t0);
    __syncthreads();
    { float4* dst=(float4*)tile;
#pragma unroll
      for(int u=0;u<6;u++){ int i=tid+u*NTHR; if(i<tc*128) dst[i]=pre[u]; } }
    __syncthreads();
    if(t0+24<lcnt){                     // issue next tile's loads (hidden under compute)
      int rem=(lcnt-t0-24)*128;
      const float4* src=base+(size_t)(t0+24)*128;
#pragma unroll
      for(int u=0;u<6;u++){ int i=tid+u*NTHR; pre[u]=(i<rem)?src[i]:make_float4(0.f,0.f,0.f,0.f); }
    }
#pragma unroll
    for(int r=0;r<3;r++){
      int row=w*3+r;
      float sc=-1e30f;
      if(row<tc){
        const float4* er=(const float4*)(tile+row*512);
        float4 e0=er[lane*2], e1=er[lane*2+1];
        float pp=q0.x*e0.x+q0.y*e0.y+q0.z*e0.z+q0.w*e0.w
                +q1.x*e1.x+q1.y*e1.y+q1.z*e1.z+q1.w*e1.w;
        pp=wredSum(pp);
        sc=p.mask[b*L_+l0+t0+row]?-1e9f:pp;
      }
      if(lane==0) sc24[row]=sc;
    }
    __syncthreads();
    float tm=-3.0e38f;
    for(int r=0;r<tc;r++) tm=fmaxf(tm,sc24[r]);
    float mn=fmaxf(m,tm);
    float scl=expf(m-mn);
    float Sadd=0.f, aadd=0.f;
    for(int r=0;r<tc;r++){
      float pe=expf(sc24[r]-mn);
      Sadd+=pe;
      aadd+=pe*tile[r*512+tid];
    }
    S=S*scl+Sadd;
    acc=acc*scl+aadd;
    m=mn;
  }
  p.cpart[(size_t)(b*6+j)*H_+tid]=acc;
  if(tid==0){p.cstat[(b*6+j)*2]=m; p.cstat[(b*6+j)*2+1]=S;}
}

// combine 6 ctx partials, project through Wv (+bv) -> att; ADD also stores attTall[t]
static __device__ void atto_ph(const P& p,float* SH,const float* Wv,const float* bv,
    bool ADD,int t){
  int tid=threadIdx.x;
  if(blockIdx.x>=40) return;
  int b=blockIdx.x;
  float mb=-3.0e38f;
#pragma unroll
  for(int j=0;j<6;j++) mb=fmaxf(mb,p.cstat[(b*6+j)*2]);
  float Sb=0.f;
#pragma unroll
  for(int j=0;j<6;j++) Sb+=p.cstat[(b*6+j)*2+1]*expf(p.cstat[(b*6+j)*2]-mb);
  float inv=1.0f/Sb;
  float cx=0.f;
#pragma unroll
  for(int j=0;j<6;j++) cx+=expf(p.cstat[(b*6+j)*2]-mb)*p.cpart[(size_t)(b*6+j)*H_+tid];
  SH[tid]=cx*inv;
  __syncthreads();
  if(tid<A_){
    float a=bv[tid];
    const float4* wr=(const float4*)(Wv+(size_t)tid*H_);
#pragma unroll 8
    for(int i=0;i<H_/4;i++){
      float4 w4=wr[i];
      a+=SH[4*i]*w4.x+SH[4*i+1]*w4.y+SH[4*i+2]*w4.z+SH[4*i+3]*w4.w;
    }
    if(ADD){
      a+=p.att1[b*A_+tid];
      p.att2[b*A_+tid]=a;
      p.attTall[(size_t)t*A_*B_+tid*B_+b]=a;
    }
    else p.att1[b*A_+tid]=a;
  }
}

// copy scores from bf16 copyK (16B/lane) -> sccAll[t]
static __device__ void copysc_ph(const P& p,int t){
  int tid=threadIdx.x,w=tid>>6,lane=tid&63;
  if(blockIdx.x>=240) return;
  int b=blockIdx.x/6, j=blockIdx.x%6;
  int l0=j*167, lcnt=min(167,L_-l0);
  float* scct=p.sccAll+(size_t)t*B_*L_;
  float ar[8];
#pragma unroll
  for(int q=0;q<8;q++){
    int a=lane*8+q;
    ar[q]=(lane<40&&a<A_)? p.att2[b*A_+a] : 0.f;
  }
  for(int l=l0+w;l<l0+lcnt;l+=8){
    float pp=0.f;
    if(lane<40){
      const uint4* cr=(const uint4*)(p.copyKh+((size_t)(b*L_+l))*320);
      uint4 kk=cr[lane];
      pp =ar[0]*__uint_as_float(kk.x<<16)+ar[1]*__uint_as_float(kk.x&0xffff0000u);
      pp+=ar[2]*__uint_as_float(kk.y<<16)+ar[3]*__uint_as_float(kk.y&0xffff0000u);
      pp+=ar[4]*__uint_as_float(kk.z<<16)+ar[5]*__uint_as_float(kk.z&0xffff0000u);
      pp+=ar[6]*__uint_as_float(kk.w<<16)+ar[7]*__uint_as_float(kk.w&0xffff0000u);
    }
    pp=wredSum(pp);
    if(lane==0) scct[b*L_+l]=p.mask[b*L_+l]?-1e9f:pp;
  }
}

// softmax(sccAll[t]) stats + sel partial only (scatter deferred)
static __device__ void sel_ph(const P& p,float* SH,float* red,int t){
  int tid=threadIdx.x,w=tid>>6,lane=tid&63;
  if(blockIdx.x>=240) return;
  int b=blockIdx.x/6, j=blockIdx.x%6;
  int l0=j*167, lcnt=min(167,L_-l0);
  const float* scct=p.sccAll+(size_t)t*B_*L_;
  for(int i=tid;i<L_;i+=NTHR) SH[i]=scct[b*L_+i];
  __syncthreads();
  float lm=-3.0e38f;
  for(int i=tid;i<L_;i+=NTHR) lm=fmaxf(lm,SH[i]);
  lm=wredMax(lm);
  if(lane==0) red[w]=lm;
  __syncthreads();
  float m=red[0];
#pragma unroll
  for(int q=1;q<8;q++) m=fmaxf(m,red[q]);
  __syncthreads();
  int so=p.inputs[b*T_+t];
  float ls=0.f,lq=0.f;
  for(int i=tid;i<L_;i+=NTHR){
    float exv=expf(SH[i]-m);
    ls+=exv;
    if(p.enc_in[b*L_+i]==so) lq+=exv;
  }
  ls=wredSum(ls); lq=wredSum(lq);
  if(lane==0){red[w]=ls; red[8+w]=lq;}
  __syncthreads();
  float S=0.f,Q=0.f;
#pragma unroll
  for(int q=0;q<8;q++){S+=red[q];Q+=red[8+q];}
  if(tid<lcnt){
    int l=l0+tid;
    float exv=expf(SH[l]-m);
    SH[1024+tid]=(p.enc_in[b*L_+l]==so)?exv:0.f;
  }
  __syncthreads();
  // sel partial: thread = (rg 0..3, h4 0..127); float4 along h
  int h4=tid&127, rg=tid>>7;
  float4 a4=make_float4(0.f,0.f,0.f,0.f);
#pragma unroll 2
  for(int li=rg;li<lcnt;li+=4){
    float wgt=SH[1024+li];
    float4 ev=*(const float4*)(p.enc+((size_t)(b*L_+l0+li))*H_+h4*4);
    a4.x+=wgt*ev.x; a4.y+=wgt*ev.y; a4.z+=wgt*ev.z; a4.w+=wgt*ev.w;
  }
  *(float4*)(SH+2048+tid*4)=a4;
  __syncthreads();
  float inv=1.0f/(Q+1e-8f*S);
  float s=SH[2048+tid]+SH[2048+512+tid]+SH[2048+1024+tid]+SH[2048+1536+tid];
  p.selp[(size_t)(b*6+j)*H_+tid]=s*inv;
}

__global__ __launch_bounds__(NTHR,2) void k_persist(P p){
  __shared__ float SH[12544];
  __shared__ float gld[512];
  __shared__ float red[16];
  int blk=blockIdx.x, tid=threadIdx.x;
  unsigned bt=0;
#define BARR() do{bt++; gbar2(p.flags,p.rel,bt);}while(0)

  // ===== PREP: M1T/M2T = Wq^T@Wk (transposed), bqk = bq@Wk =====
  {
    int mm=blk>>7, r0=(blk&127)*4;
    const float* Wq = mm? p.a2Wq : p.a1Wq;
    const float* Wk = mm? p.a2Wk : p.a1Wk;
    float* MT = mm? p.M2T : p.M1T;
    float s0=0.f,s1=0.f,s2=0.f,s3=0.f;
    for(int a=0;a<A_;a++){
      float wq=Wq[a*H_+tid];
      s0+=wq*Wk[a*H_+r0+0];
      s1+=wq*Wk[a*H_+r0+1];
      s2+=wq*Wk[a*H_+r0+2];
      s3+=wq*Wk[a*H_+r0+3];
    }
    MT[(size_t)(r0+0)*H_+tid]=s0;
    MT[(size_t)(r0+1)*H_+tid]=s1;
    MT[(size_t)(r0+2)*H_+tid]=s2;
    MT[(size_t)(r0+3)*H_+tid]=s3;
    if((blk&127)==0){
      const float* bq = mm? p.a2bq : p.a1bq;
      float ab=0.f;
      for(int a=0;a<A_;a++) ab+=bq[a]*Wk[a*H_+tid];
      (mm? p.bqk2 : p.bqk1)[tid]=ab;
    }
  }
  // ===== PREP: copyKh = bf16(tanh(enc @ cW^T + cb)), rows padded to 320 =====
  for(int item=blk;item<B_*63;item+=NBLK){
    int b=item/63, lt=item-b*63;
    int l0=lt*16, lcnt=min(16,L_-l0);
    float acc[16];
    float bv=(tid<A_)?p.cb[tid]:0.f;
#pragma unroll
    for(int l=0;l<16;l++) acc[l]=bv;
    for(int k0=0;k0<H_;k0+=32){
      __syncthreads();
      for(int i=tid;i<A_*32;i+=NTHR){
        int a=i>>5,kc=i&31;
        SH[a*33+kc]=p.cW[(size_t)a*H_+k0+kc];
      }
      __syncthreads();
      if(tid<A_){
#pragma unroll
        for(int l=0;l<16;l++){
          if(l<lcnt){
            const float* es=p.enc+((size_t)(b*L_+l0+l))*H_+k0;
            float al=acc[l];
#pragma unroll
            for(int kc=0;kc<32;kc++) al+=SH[tid*33+kc]*es[kc];
            acc[l]=al;
          }
        }
      }
    }
    if(tid<320){
#pragma unroll
      for(int l=0;l<16;l++){
        if(l<lcnt){
          unsigned short hv=0;
          if(tid<A_) hv=f2bf(tanhf(acc[l]));
          p.copyKh[((size_t)(b*L_+l0+l))*320+tid]=hv;
        }
      }
    }
  }
  BARR();

  // ===== recurrent decoder steps (no vocab/scatter/argmax) =====
  for(int t=0;t<T_;t++){
    int rp=t&1, wp=rp^1;
    float* stt=p.stt;
    auto SL=[&](int i,int par){ return stt+((size_t)(i*2+par))*(B_*H_); };
    float *eh1r=SL(0,rp),*eh1w=SL(0,wp),*ec1r=SL(1,rp),*ec1w=SL(1,wp);
    float *eh2r=SL(2,rp),*eh2w=SL(2,wp),*ec2r=SL(3,rp),*ec2w=SL(3,wp);
    float *h1r=SL(4,rp),*h1w=SL(4,wp),*c1r=SL(5,rp),*c1w=SL(5,wp);
    float *h2r=SL(6,rp),*h2w=SL(6,wp),*c2r=SL(7,rp),*c2w=SL(7,wp);

    lstm_ph(p,SH,gld,t,p.e1Wih,E_,p.e1Whh,p.e1b,nullptr,true ,eh1r,ec1r,eh1w,ec1w); BARR();
    lstm_ph(p,SH,gld,t,p.e2Wih,H_,p.e2Whh,p.e2b,eh1w  ,false,eh2r,ec2r,eh2w,ec2w); BARR();

    { // dec_in = concat(emb, eh2, att2_prev, sel_prev) @ in_W^T + in_b + pe
      int w=tid>>6,lane=tid&63;
      int usub=w>>2, kq=w&3;
      int unit=blk*2+usub;
      int rowu=__builtin_amdgcn_readfirstlane(unit);
      float acc=0.f;
      const float* Wr=p.inW+(size_t)rowu*1624;
      const int* inp=p.inputs; const float* emb=p.embed;
      const float* e2=eh2w; const float* a2c=p.att2; const float* sp=p.selp;
      int tt=t;
      gv_accum(SH,1624,Wr,acc,lane,kq,4,[=](int bb,int kk)->float{
        if(kk<E_){int si=(tt==0)?START_:inp[bb*T_+tt-1];return emb[(size_t)si*E_+kk];}
        else if(kk<E_+H_) return e2[bb*H_+kk-E_];
        else if(kk<E_+H_+A_) return a2c[bb*A_+kk-(E_+H_)];
        else{
          int hh=kk-(E_+H_+A_); float s=0.f;
#pragma unroll
          for(int jj=0;jj<6;jj++) s+=sp[(size_t)(bb*6+jj)*H_+hh];
          return s;
        }
      });
      gld[(usub*4+kq)*64+lane]=acc;
      __syncthreads();
      if(w<2&&lane<40){
        int u=blk*2+w;
        float s=gld[(w*4+0)*64+lane]+gld[(w*4+1)*64+lane]
               +gld[(w*4+2)*64+lane]+gld[(w*4+3)*64+lane];
        float ex=(float)(2*(u>>1))/512.0f;
        float ang=(float)t/powf(10000.0f,ex);
        s+=p.inb[u]+((u&1)?cosf(ang):sinf(ang));
        p.dec[lane*H_+u]=s;
      }
      __syncthreads();
    }
    BARR();

    lstm_ph(p,SH,gld,t,p.r1Wih,H_,p.r1Whh,p.r1b,p.dec ,false,h1r,c1r,h1w,c1w); BARR();
    qk_ph(p,SH,h1w,p.M1T,p.bqk1);                                              BARR();
    scctx_ph(p,SH);                                                            BARR();
    atto_ph(p,SH,p.a1Wv,p.a1bv,false,t);                                       BARR();
    lstm_ph(p,SH,gld,t,p.r2Wih,A_,p.r2Whh,p.r2b,p.att1,false,h2r,c2r,h2w,c2w); BARR();
    qk_ph(p,SH,h2w,p.M2T,p.bqk2);                                              BARR();
    scctx_ph(p,SH);                                                            BARR();
    atto_ph(p,SH,p.a2Wv,p.a2bv,true,t);                                        BARR();
    copysc_ph(p,t);                                                            BARR();
    sel_ph(p,SH,red,t);                                                        BARR();
  }

  // ===== FINAL A: vocab logits for ALL t, balanced (v-tile, t) items =====
  {
    int row=tid>>1, half=tid&1;
    for(int item=blk;item<NVT*T_;item+=NBLK){
      int vt=item/T_, t=item-vt*T_;
      long v0=(long)vt*256;
      int vcnt=min(256,(int)(V_-v0));
      float acc[20];
#pragma unroll
      for(int q=0;q<20;q++) acc[q]=0.f;
      for(int c=0;c<10;c++){
        int a0=c*32, aw=min(32,A_-a0);
        __syncthreads();
        if(c<9){
          int tot=vcnt*8;
          for(int i=tid;i<tot;i+=NTHR){
            int vr=i>>3, f=i&7;
            *(float4*)&SH[vr*36+f*4]=*(const float4*)(p.oW+(size_t)(v0+vr)*A_+a0+f*4);
          }
          for(int i=tid;i<32*40;i+=NTHR) SH[9216+i]=p.attTall[(size_t)t*A_*B_+a0*B_+i];
        } else {
          int tot=vcnt*3;
          for(int i=tid;i<tot;i+=NTHR){
            int vr=i/3, f=i-vr*3;
            *(float4*)&SH[vr*36+f*4]=*(const float4*)(p.oW+(size_t)(v0+vr)*A_+a0+f*4);
          }
          for(int i=tid;i<12*40;i+=NTHR) SH[9216+i]=p.attTall[(size_t)t*A_*B_+a0*B_+i];
        }
        __syncthreads();
        if(row<vcnt){
          const float* wrow=&SH[row*36];
          for(int ac=0;ac<aw;ac++){
            float wv=wrow[ac];
            const float* at=&SH[9216+ac*40+half*20];
#pragma unroll
            for(int bq=0;bq<5;bq++){
              float4 t4=*(const float4*)(at+bq*4);
              acc[bq*4+0]+=wv*t4.x; acc[bq*4+1]+=wv*t4.y;
              acc[bq*4+2]+=wv*t4.z; acc[bq*4+3]+=wv*t4.w;
            }
          }
        }
      }
      if(row<vcnt){
        long v=v0+row;
        float obv=p.ob[v];
#pragma unroll
        for(int bb=0;bb<20;bb++){
          int b=half*20+bb;
          p.dout[((size_t)(b*T_+t))*V_+v]=acc[bb]+obv;
        }
      }
    }
  }
  BARR();

  // ===== FINAL B: deferred scatter adds =====
  {
    int w=tid>>6,lane=tid&63;
    float sc2=p.scale[0]*p.scale[0];
    for(int it=blk;it<B_*T_;it+=NBLK){
      int b=it/T_, t=it-b*T_;
      const float* scr=p.sccAll+((size_t)t*B_+b)*L_;
      __syncthreads();
      for(int i=tid;i<L_;i+=NTHR) SH[i]=scr[i];
      __syncthreads();
      float lm=-3.0e38f;
      for(int i=tid;i<L_;i+=NTHR) lm=fmaxf(lm,SH[i]);
      lm=wredMax(lm);
      if(lane==0) red[w]=lm;
      __syncthreads();
      float m=red[0];
#pragma unroll
      for(int q=1;q<8;q++) m=fmaxf(m,red[q]);
      __syncthreads();
      float ls=0.f;
      for(int i=tid;i<L_;i+=NTHR) ls+=expf(SH[i]-m);
      ls=wredSum(ls);
      if(lane==0) red[w]=ls;
      __syncthreads();
      float S=0.f;
#pragma unroll
      for(int q=0;q<8;q++) S+=red[q];
      float f=sc2/S;
      float* drow=p.dout+((size_t)(b*T_+t))*V_;
      const int* ei=p.enc_in+b*L_;
      for(int i=tid;i<L_;i+=NTHR) atomicAdd(drow+ei[i], expf(SH[i]-m)*f);
      __syncthreads();
    }
  }
  BARR();

  // ===== FINAL C: argmax per (b,t) row -> syms =====
  {
    int* isa=(int*)(SH+512);
    for(int it=blk;it<B_*T_;it+=NBLK){
      int b=it/T_, t=it-b*T_;
      const float* row=p.dout+((size_t)(b*T_+t))*V_;
      float best=-3.0e38f; int bi=0;
      for(int i4=tid;i4<V_/4;i4+=NTHR){
        float4 x=((const float4*)row)[i4];
        int base=i4*4;
        if(x.x>best){best=x.x;bi=base;}
        if(x.y>best){best=x.y;bi=base+1;}
        if(x.z>best){best=x.z;bi=base+2;}
        if(x.w>best){best=x.w;bi=base+3;}
      }
      __syncthreads();
      SH[tid]=best; isa[tid]=bi;
      __syncthreads();
      for(int off=256;off>0;off>>=1){
        if(tid<off){
          float ov=SH[tid+off]; int oi=isa[tid+off];
          if(ov>SH[tid]||(ov==SH[tid]&&oi<isa[tid])){SH[tid]=ov; isa[tid]=oi;}
        }
        __syncthreads();
      }
      if(tid==0) p.dout[(size_t)B_*T_*V_+b*T_+t]=(float)isa[0];
    }
  }
#undef BARR
}

extern "C" void kernel_launch(void* const* d_in, const int* in_sizes, int n_in,
                              void* d_out, int out_size, void* d_ws, size_t ws_size,
                              hipStream_t stream){
  P p;
  p.enc_in=(const int*)d_in[0];
  p.enc   =(const float*)d_in[1];
  p.mask  =(const unsigned char*)d_in[2];
  p.inputs=(const int*)d_in[3];
  p.embed =(const float*)d_in[4];
  p.e1Wih=(const float*)d_in[5];  p.e1Whh=(const float*)d_in[6];  p.e1b=(const float*)d_in[7];
  p.e2Wih=(const float*)d_in[8];  p.e2Whh=(const float*)d_in[9];  p.e2b=(const float*)d_in[10];
  p.inW  =(const float*)d_in[11]; p.inb  =(const float*)d_in[12];
  p.r1Wih=(const float*)d_in[13]; p.r1Whh=(const float*)d_in[14]; p.r1b=(const float*)d_in[15];
  p.a1Wq =(const float*)d_in[16]; p.a1bq =(const float*)d_in[17];
  p.a1Wk =(const float*)d_in[18];
  p.a1Wv =(const float*)d_in[20]; p.a1bv =(const float*)d_in[21];
  p.r2Wih=(const float*)d_in[22]; p.r2Whh=(const float*)d_in[23]; p.r2b=(const float*)d_in[24];
  p.a2Wq =(const float*)d_in[25]; p.a2bq =(const float*)d_in[26];
  p.a2Wk =(const float*)d_in[27];
  p.a2Wv =(const float*)d_in[29]; p.a2bv =(const float*)d_in[30];
  p.cW   =(const float*)d_in[31]; p.cb   =(const float*)d_in[32];
  p.oW   =(const float*)d_in[33]; p.ob   =(const float*)d_in[34];
  p.scale=(const float*)d_in[35];
  p.dout=(float*)d_out;

  float* w=(float*)d_ws;
  p.copyKh=(unsigned short*)(w+OFF_CKH);
  p.M1T  =w+OFF_M1T;    p.M2T =w+OFF_M2T;
  p.bqk1 =w+OFF_BQK1;   p.bqk2=w+OFF_BQK2;
  p.qk   =w+OFF_QK;     p.dec =w+OFF_DEC;
  p.att1 =w+OFF_ATT1;
  p.cpart=w+OFF_CPART;  p.cstat=w+OFF_CSTAT;
  p.attTall=w+OFF_ATTA; p.sccAll=w+OFF_SCCA;
  p.stt  =w+OFF_STT;
  p.att2 =w+OFF_ATT2;   p.selp=w+OFF_SELP;
  p.flags=(unsigned*)(w+OFF_FLAGS);
  p.rel  =(unsigned*)(w+OFF_REL);

  // zero: LSTM states (both parities), att2 carry, sel partials, barrier flags/release
  hipMemsetAsync(w+OFF_STT,0,(WS_END-OFF_STT)*sizeof(float),stream);
  k_persist<<<NBLK,NTHR,0,stream>>>(p);
}

// Round 10
// 15614.055 us; speedup vs baseline: 1.1950x; 1.0305x over previous
//
#include <hip/hip_runtime.h>
#include <math.h>

#define B_ 40
#define L_ 1000
#define H_ 512
#define A_ 300
#define T_ 20
#define E_ 300
#define V_ 78864
#define START_ 2

#define NBLK 256
#define NTHR 1024
#define NVT 309            /* ceil(V/256) */

// ---------------- workspace layout (float offsets) ----------------
#define OFF_CKH   0ul          /* bf16 copyK, padded [B][L][320] ushort */
#define OFF_M1T   6400000ul
#define OFF_M2T   6662144ul
#define OFF_BQK1  6924288ul
#define OFF_BQK2  6924800ul
#define OFF_QK    6925312ul
#define OFF_DEC   6945792ul
#define OFF_ATT1  6966272ul
#define OFF_CPART 6978272ul    /* 40*6*512 */
#define OFF_CSTAT 7101152ul    /* 40*6*2 */
#define OFF_ATTA  7101632ul    /* attTall [T][A][B] = 240000 */
#define OFF_SCCA  7341632ul    /* sccAll  [T][B][L] = 800000 */
#define OFF_STT   8141632ul    /* zero region starts here */
#define OFF_ATT2  8469312ul
#define OFF_SELP  8481312ul    /* 40*6*512 unnormalized P */
#define OFF_SELST 8604192ul    /* 40*6*3 (m,S,Q) */
#define OFF_FLAGS 8604912ul    /* 256 flags at 32-uint stride */
#define OFF_REL   8613104ul
#define WS_END    8613168ul

struct P {
  const int* enc_in; const float* enc; const unsigned char* mask; const int* inputs;
  const float* embed;
  const float *e1Wih,*e1Whh,*e1b,*e2Wih,*e2Whh,*e2b;
  const float *inW,*inb;
  const float *r1Wih,*r1Whh,*r1b;
  const float *a1Wq,*a1bq,*a1Wk,*a1Wv,*a1bv;
  const float *r2Wih,*r2Whh,*r2b;
  const float *a2Wq,*a2bq,*a2Wk,*a2Wv,*a2bv;
  const float *cW,*cb,*oW,*ob,*scale;
  float* dout;
  unsigned short* copyKh;
  float *M1T,*M2T,*bqk1,*bqk2,*qk,*dec,*att1,*cpart,*cstat,*attTall,*sccAll,*stt,*att2,*selp,*selstat;
  unsigned *flags,*rel;
};

__device__ __forceinline__ float sigm(float x){ return 1.0f/(1.0f+expf(-x)); }

__device__ __forceinline__ float wredSum(float v){
#pragma unroll
  for(int o=32;o>0;o>>=1) v+=__shfl_xor(v,o);
  return v;
}
__device__ __forceinline__ float wredMax(float v){
#pragma unroll
  for(int o=32;o>0;o>>=1) v=fmaxf(v,__shfl_xor(v,o));
  return v;
}
__device__ __forceinline__ unsigned short f2bf(float f){
  unsigned u=__float_as_uint(f);
  u=(u+0x7fffu+((u>>16)&1u))>>16;
  return (unsigned short)u;
}

// flag/coordinator grid barrier (256 blocks)
__device__ __forceinline__ void gbar2(unsigned* flags, unsigned* rel, unsigned epoch){
  __syncthreads();
  int tid=threadIdx.x;
  if(blockIdx.x==0){
    if(tid>0 && tid<NBLK){
      while(__hip_atomic_load(flags+(unsigned)tid*32u,__ATOMIC_RELAXED,__HIP_MEMORY_SCOPE_AGENT)<epoch)
        __builtin_amdgcn_s_sleep(8);
      (void)__hip_atomic_load(flags+(unsigned)tid*32u,__ATOMIC_ACQUIRE,__HIP_MEMORY_SCOPE_AGENT);
    }
    __syncthreads();
    if(tid==0)
      __hip_atomic_store(rel,epoch,__ATOMIC_RELEASE,__HIP_MEMORY_SCOPE_AGENT);
  } else {
    if(tid==0){
      __hip_atomic_store(flags+(unsigned)blockIdx.x*32u,epoch,__ATOMIC_RELEASE,__HIP_MEMORY_SCOPE_AGENT);
      while(__hip_atomic_load(rel,__ATOMIC_RELAXED,__HIP_MEMORY_SCOPE_AGENT)<epoch)
        __builtin_amdgcn_s_sleep(8);
      (void)__hip_atomic_load(rel,__ATOMIC_ACQUIRE,__HIP_MEMORY_SCOPE_AGENT);
    }
    __syncthreads();
  }
}

// batched-40 GEMV accumulate; xs: LDS [40*257]; lane<40 = batch index.
template<typename SRC>
static __device__ __forceinline__ void gv_accum(float* xs,int K,const float* Wrow,
    float& acc,int lane,int kq,int nq,SRC src){
  for(int k0=0;k0<K;k0+=256){
    int ch=min(256,K-k0);
    __syncthreads();
    if(ch==256){
      float r[10];
#pragma unroll
      for(int u=0;u<10;u++){ int i=threadIdx.x+u*NTHR; r[u]=src(i>>8,k0+(i&255)); }
#pragma unroll
      for(int u=0;u<10;u++){ int i=threadIdx.x+u*NTHR; xs[(i>>8)*257+(i&255)]=r[u]; }
    } else {
      for(int i=threadIdx.x;i<40*ch;i+=NTHR){
        int bb=i/ch, kk=i-bb*ch;
        xs[bb*257+kk]=src(bb,k0+kk);
      }
    }
    __syncthreads();
    if(lane<40){
      float a0=0.f,a1=0.f,a2=0.f,a3=0.f;
      int k=kq;
      for(;k+3*nq<ch;k+=4*nq){
        a0+=Wrow[k0+k     ]*xs[lane*257+k];
        a1+=Wrow[k0+k+  nq]*xs[lane*257+k+  nq];
        a2+=Wrow[k0+k+2*nq]*xs[lane*257+k+2*nq];
        a3+=Wrow[k0+k+3*nq]*xs[lane*257+k+3*nq];
      }
      for(;k<ch;k+=nq) a0+=Wrow[k0+k]*xs[lane*257+k];
      acc+=a0+a1+a2+a3;
    }
  }
}

// LSTM all 40 b: block = 2 units; 16 waves = 2 units x 4 gates x 2 ksplits
static __device__ void lstm_ph(const P& p,float* SH,float* gld,int t,
    const float* Wih,int XD,const float* Whh,const float* bias,
    const float* xvec,bool gather,
    const float* hr,const float* cr,float* hw,float* cw){
  int tid=threadIdx.x,w=tid>>6,lane=tid&63;
  int gate=w&3,ks=(w>>2)&1,usub=w>>3;
  int row=gate*H_+(blockIdx.x*2+usub);
  int rowu=__builtin_amdgcn_readfirstlane(row);
  float acc=0.f;
  const float* W1=Wih+(size_t)rowu*XD;
  if(gather){
    const int* inp=p.inputs; const float* emb=p.embed; int tt=t;
    gv_accum(SH,XD,W1,acc,lane,ks,2,[=](int bb,int kk)->float{
      int si=(tt==0)?START_:inp[bb*T_+tt-1];
      return emb[(size_t)si*E_+kk];});
  }else{
    gv_accum(SH,XD,W1,acc,lane,ks,2,[=](int bb,int kk)->float{
      return xvec[(size_t)bb*XD+kk];});
  }
  const float* W2=Whh+(size_t)rowu*H_;
  gv_accum(SH,H_,W2,acc,lane,ks,2,[=](int bb,int kk)->float{
    return hr[bb*H_+kk];});
  gld[w*64+lane]=acc;
  __syncthreads();
  if(w<2&&lane<40){
    int u=blockIdx.x*2+w,b=lane;
    float g0=gld[((w<<3)|0)*64+b]+gld[((w<<3)|4)*64+b]+bias[0*H_+u];
    float g1=gld[((w<<3)|1)*64+b]+gld[((w<<3)|5)*64+b]+bias[1*H_+u];
    float g2=gld[((w<<3)|2)*64+b]+gld[((w<<3)|6)*64+b]+bias[2*H_+u];
    float g3=gld[((w<<3)|3)*64+b]+gld[((w<<3)|7)*64+b]+bias[3*H_+u];
    float c=cr[b*H_+u];
    float cn=sigm(g1)*c+sigm(g0)*tanhf(g2);
    hw[b*H_+u]=sigm(g3)*tanhf(cn);
    cw[b*H_+u]=cn;
  }
  __syncthreads();
}

// qk[b][h'] = bqk[h'] + hsrc[b,:].MT[h',:]; 2 threads per row
static __device__ void qk_ph(const P& p,float* SH,const float* hsrc,
    const float* MT,const float* bqk){
  int tid=threadIdx.x;
  if(blockIdx.x>=240) return;
  int b=blockIdx.x/6, j=blockIdx.x%6;
  if(tid<512) SH[tid]=hsrc[b*H_+tid];
  __syncthreads();
  int rp2=tid>>1, hf=tid&1;
  int h0=j*86, hc=min(86,H_-h0);
  if(rp2<hc){
    int hp=h0+rp2;
    const float4* mr=(const float4*)(MT+(size_t)hp*H_)+hf*64;
    const float4* hs=((const float4*)SH)+hf*64;
    float a=0.f;
#pragma unroll 16
    for(int i=0;i<64;i++){
      float4 m4=mr[i],h4=hs[i];
      a+=m4.x*h4.x+m4.y*h4.y+m4.z*h4.z+m4.w*h4.w;
    }
    a+=__shfl_xor(a,1);
    if(hf==0) p.qk[b*H_+hp]=a+bqk[hp];
  }
}

// fused scores + online-softmax ctx partial; 32-row tiles, reg prefetch,
// merge split across thread pairs (h=tid>>1, row-half=tid&1)
static __device__ void scctx_ph(const P& p,float* SH){
  int tid=threadIdx.x,w=tid>>6,lane=tid&63;
  if(blockIdx.x>=240) return;
  int b=blockIdx.x/6, j=blockIdx.x%6;
  int l0=j*167, lcnt=min(167,L_-l0);
  const float* qrow=p.qk+b*H_;
  float4 q0=*(const float4*)(qrow+lane*8);
  float4 q1=*(const float4*)(qrow+lane*8+4);
  float* tile=SH;            // [32*512]
  float* sc32=SH+16384;      // [32]
  const float4* base=(const float4*)(p.enc+((size_t)(b*L_+l0))*H_);
  float4 pre[4];
  { int rem=lcnt*128;
#pragma unroll
    for(int u=0;u<4;u++){ int i=tid+u*NTHR; pre[u]=(i<rem)?base[i]:make_float4(0.f,0.f,0.f,0.f); } }
  int h=tid>>1, rh=tid&1;
  float m=-3.0e38f,S=0.f,acc=0.f;
  for(int t0=0;t0<lcnt;t0+=32){
    int tc=min(32,lcnt-t0);
    __syncthreads();
    { float4* dst=(float4*)tile;
#pragma unroll
      for(int u=0;u<4;u++){ int i=tid+u*NTHR; if(i<tc*128) dst[i]=pre[u]; } }
    __syncthreads();
    if(t0+32<lcnt){
      int rem=(lcnt-t0-32)*128;
      const float4* src=base+(size_t)(t0+32)*128;
#pragma unroll
      for(int u=0;u<4;u++){ int i=tid+u*NTHR; pre[u]=(i<rem)?src[i]:make_float4(0.f,0.f,0.f,0.f); }
    }
#pragma unroll
    for(int r=0;r<2;r++){
      int row=w*2+r;
      float sc=-1e30f;
      if(row<tc){
        const float4* er=(const float4*)(tile+row*512);
        float4 e0=er[lane*2], e1=er[lane*2+1];
        float pp=q0.x*e0.x+q0.y*e0.y+q0.z*e0.z+q0.w*e0.w
                +q1.x*e1.x+q1.y*e1.y+q1.z*e1.z+q1.w*e1.w;
        pp=wredSum(pp);
        sc=p.mask[b*L_+l0+t0+row]?-1e9f:pp;
      }
      if(lane==0) sc32[row]=sc;
    }
    __syncthreads();
    float tm=-3.0e38f;
    for(int r=0;r<tc;r++) tm=fmaxf(tm,sc32[r]);
    float mn=fmaxf(m,tm);
    float scl=expf(m-mn);
    float Sa=0.f, aa=0.f;
    for(int r=rh;r<tc;r+=2){
      float pe=expf(sc32[r]-mn);
      Sa+=pe;
      aa+=pe*tile[r*512+h];
    }
    S=S*scl+Sa;
    acc=acc*scl+aa;
    m=mn;
  }
  S+=__shfl_xor(S,1);
  acc+=__shfl_xor(acc,1);
  if(rh==0) p.cpart[(size_t)(b*6+j)*H_+h]=acc;
  if(tid==0){p.cstat[(b*6+j)*2]=m; p.cstat[(b*6+j)*2+1]=S;}
}

// combine 6 ctx partials, project through Wv (+bv) -> att
static __device__ void atto_ph(const P& p,float* SH,const float* Wv,const float* bv,
    bool ADD,int t){
  int tid=threadIdx.x;
  if(blockIdx.x>=40) return;
  int b=blockIdx.x;
  float mb=-3.0e38f;
#pragma unroll
  for(int j=0;j<6;j++) mb=fmaxf(mb,p.cstat[(b*6+j)*2]);
  float Sb=0.f;
#pragma unroll
  for(int j=0;j<6;j++) Sb+=p.cstat[(b*6+j)*2+1]*expf(p.cstat[(b*6+j)*2]-mb);
  float inv=1.0f/Sb;
  if(tid<512){
    float cx=0.f;
#pragma unroll
    for(int j=0;j<6;j++) cx+=expf(p.cstat[(b*6+j)*2]-mb)*p.cpart[(size_t)(b*6+j)*H_+tid];
    SH[tid]=cx*inv;
  }
  __syncthreads();
  int rp2=tid>>1, hf=tid&1;
  if(rp2<A_){
    const float4* wr=(const float4*)(Wv+(size_t)rp2*H_)+hf*64;
    const float4* cs=((const float4*)SH)+hf*64;
    float a=0.f;
#pragma unroll 16
    for(int i=0;i<64;i++){
      float4 w4=wr[i],c4=cs[i];
      a+=w4.x*c4.x+w4.y*c4.y+w4.z*c4.z+w4.w*c4.w;
    }
    a+=__shfl_xor(a,1);
    if(hf==0){
      a+=bv[rp2];
      if(ADD){
        a+=p.att1[b*A_+rp2];
        p.att2[b*A_+rp2]=a;
        p.attTall[(size_t)t*A_*B_+rp2*B_+b]=a;
      } else p.att1[b*A_+rp2]=a;
    }
  }
}

// fused copy scores + chunk-local sel stats & sparse sel partial
static __device__ void copyscsel_ph(const P& p,float* SH,float* red,int t){
  int tid=threadIdx.x,w=tid>>6,lane=tid&63;
  if(blockIdx.x>=240) return;
  int b=blockIdx.x/6, j=blockIdx.x%6;
  int l0=j*167, lcnt=min(167,L_-l0);
  float* scct=p.sccAll+(size_t)t*B_*L_;
  float* sccL=SH;            // [176]
  float* sccE=SH+176;        // [176] eq-masked exp values
  int* nzc=(int*)(SH+352);
  int* nzl=(int*)(SH+356);   // [176]
  if(tid==0) *nzc=0;
  float ar[8];
#pragma unroll
  for(int q=0;q<8;q++){
    int a=lane*8+q;
    ar[q]=(lane<40&&a<A_)? p.att2[b*A_+a] : 0.f;
  }
  float mw=-3.0e38f;
  for(int l=l0+w;l<l0+lcnt;l+=16){
    float pp=0.f;
    if(lane<40){
      const uint4* cr=(const uint4*)(p.copyKh+((size_t)(b*L_+l))*320);
      uint4 kk=cr[lane];
      pp =ar[0]*__uint_as_float(kk.x<<16)+ar[1]*__uint_as_float(kk.x&0xffff0000u);
      pp+=ar[2]*__uint_as_float(kk.y<<16)+ar[3]*__uint_as_float(kk.y&0xffff0000u);
      pp+=ar[4]*__uint_as_float(kk.z<<16)+ar[5]*__uint_as_float(kk.z&0xffff0000u);
      pp+=ar[6]*__uint_as_float(kk.w<<16)+ar[7]*__uint_as_float(kk.w&0xffff0000u);
    }
    pp=wredSum(pp);
    float v=p.mask[b*L_+l]?-1e9f:pp;
    if(lane==0){ scct[b*L_+l]=v; sccL[l-l0]=v; }
    mw=fmaxf(mw,v);
  }
  if(lane==0) red[w]=mw;
  __syncthreads();
  float m=red[0];
#pragma unroll
  for(int q=1;q<16;q++) m=fmaxf(m,red[q]);
  __syncthreads();
  int so=p.inputs[b*T_+t];
  float e=0.f,qe=0.f;
  if(tid<lcnt){
    e=expf(sccL[tid]-m);
    bool eq=(p.enc_in[b*L_+l0+tid]==so);
    sccE[tid]=eq?e:0.f;
    if(eq){ int k=atomicAdd(nzc,1); nzl[k]=tid; qe=e; }
  }
  float ls=wredSum(e), lq=wredSum(qe);
  if(lane==0){ red[w]=ls; red[16+w]=lq; }
  __syncthreads();
  float S=0.f,Q=0.f;
#pragma unroll
  for(int q=0;q<16;q++){S+=red[q];Q+=red[16+q];}
  int nz=*nzc;
  if(tid<512){
    float pp=0.f;
    for(int k=0;k<nz;k++){
      int row=nzl[k];
      pp+=sccE[row]*p.enc[((size_t)(b*L_+l0+row))*H_+tid];
    }
    p.selp[(size_t)(b*6+j)*H_+tid]=pp;
  }
  if(tid==0){
    p.selstat[(size_t)(b*6+j)*3+0]=m;
    p.selstat[(size_t)(b*6+j)*3+1]=S;
    p.selstat[(size_t)(b*6+j)*3+2]=Q;
  }
}

__global__ __launch_bounds__(NTHR) void k_rec(P p){
  __shared__ float SH[16448];
  __shared__ float gld[1024];
  __shared__ float red[32];
  __shared__ float ssc[240];
  int blk=blockIdx.x, tid=threadIdx.x;
  unsigned bt=0;
#define BARR() do{bt++; gbar2(p.flags,p.rel,bt);}while(0)

  // ===== PREP: M1T/M2T = Wq^T@Wk (transposed), bqk = bq@Wk =====
  if(tid<512){
    int mm=blk>>7, r0=(blk&127)*4;
    const float* Wq = mm? p.a2Wq : p.a1Wq;
    const float* Wk = mm? p.a2Wk : p.a1Wk;
    float* MT = mm? p.M2T : p.M1T;
    float s0=0.f,s1=0.f,s2=0.f,s3=0.f;
    for(int a=0;a<A_;a++){
      float wq=Wq[a*H_+tid];
      s0+=wq*Wk[a*H_+r0+0];
      s1+=wq*Wk[a*H_+r0+1];
      s2+=wq*Wk[a*H_+r0+2];
      s3+=wq*Wk[a*H_+r0+3];
    }
    MT[(size_t)(r0+0)*H_+tid]=s0;
    MT[(size_t)(r0+1)*H_+tid]=s1;
    MT[(size_t)(r0+2)*H_+tid]=s2;
    MT[(size_t)(r0+3)*H_+tid]=s3;
    if((blk&127)==0){
      const float* bq = mm? p.a2bq : p.a1bq;
      float ab=0.f;
      for(int a=0;a<A_;a++) ab+=bq[a]*Wk[a*H_+tid];
      (mm? p.bqk2 : p.bqk1)[tid]=ab;
    }
  }
  // ===== PREP: copyKh = bf16(tanh(enc @ cW^T + cb)), rows padded to 320 =====
  for(int item=blk;item<B_*63;item+=NBLK){
    int b=item/63, lt=item-b*63;
    int l0=lt*16, lcnt=min(16,L_-l0);
    float acc[16];
    float bv=(tid<A_)?p.cb[tid]:0.f;
#pragma unroll
    for(int l=0;l<16;l++) acc[l]=bv;
    for(int k0=0;k0<H_;k0+=32){
      __syncthreads();
      for(int i=tid;i<A_*32;i+=NTHR){
        int a=i>>5,kc=i&31;
        SH[a*33+kc]=p.cW[(size_t)a*H_+k0+kc];
      }
      __syncthreads();
      if(tid<A_){
#pragma unroll
        for(int l=0;l<16;l++){
          if(l<lcnt){
            const float* es=p.enc+((size_t)(b*L_+l0+l))*H_+k0;
            float al=acc[l];
#pragma unroll
            for(int kc=0;kc<32;kc++) al+=SH[tid*33+kc]*es[kc];
            acc[l]=al;
          }
        }
      }
    }
    if(tid<320){
#pragma unroll
      for(int l=0;l<16;l++){
        if(l<lcnt){
          unsigned short hv=0;
          if(tid<A_) hv=f2bf(tanhf(acc[l]));
          p.copyKh[((size_t)(b*L_+l0+l))*320+tid]=hv;
        }
      }
    }
  }
  BARR();

  // ===== recurrent steps =====
  for(int t=0;t<T_;t++){
    int rp=t&1, wp=rp^1;
    float* stt=p.stt;
    auto SL=[&](int i,int par){ return stt+((size_t)(i*2+par))*(B_*H_); };
    float *eh1r=SL(0,rp),*eh1w=SL(0,wp),*ec1r=SL(1,rp),*ec1w=SL(1,wp);
    float *eh2r=SL(2,rp),*eh2w=SL(2,wp),*ec2r=SL(3,rp),*ec2w=SL(3,wp);
    float *h1r=SL(4,rp),*h1w=SL(4,wp),*c1r=SL(5,rp),*c1w=SL(5,wp);
    float *h2r=SL(6,rp),*h2w=SL(6,wp),*c2r=SL(7,rp),*c2w=SL(7,wp);

    lstm_ph(p,SH,gld,t,p.e1Wih,E_,p.e1Whh,p.e1b,nullptr,true ,eh1r,ec1r,eh1w,ec1w); BARR();
    lstm_ph(p,SH,gld,t,p.e2Wih,H_,p.e2Whh,p.e2b,eh1w  ,false,eh2r,ec2r,eh2w,ec2w); BARR();

    { // dec_in: combine sel chunk stats, then batched GEMV
      if(tid<40){
        float mj[6],Sj[6],Qj[6];
#pragma unroll
        for(int jj=0;jj<6;jj++){
          mj[jj]=p.selstat[(size_t)(tid*6+jj)*3+0];
          Sj[jj]=p.selstat[(size_t)(tid*6+jj)*3+1];
          Qj[jj]=p.selstat[(size_t)(tid*6+jj)*3+2];
        }
        float ms=mj[0];
#pragma unroll
        for(int jj=1;jj<6;jj++) ms=fmaxf(ms,mj[jj]);
        float Ss=0.f,Qs=0.f;
#pragma unroll
        for(int jj=0;jj<6;jj++){ float ee=expf(mj[jj]-ms); Ss+=ee*Sj[jj]; Qs+=ee*Qj[jj]; }
        float inv=(Ss>0.f)?1.0f/(Qs+1e-8f*Ss):0.f;
#pragma unroll
        for(int jj=0;jj<6;jj++) ssc[tid*6+jj]=expf(mj[jj]-ms)*inv;
      }
      int w=tid>>6,lane=tid&63;
      int usub=w>>3, kq=w&7;
      int unit=blk*2+usub;
      int rowu=__builtin_amdgcn_readfirstlane(unit);
      float acc=0.f;
      const float* Wr=p.inW+(size_t)rowu*1624;
      const int* inp=p.inputs; const float* emb=p.embed;
      const float* e2=eh2w; const float* a2c=p.att2; const float* sp=p.selp;
      float* sscl=ssc;
      int tt=t;
      gv_accum(SH,1624,Wr,acc,lane,kq,8,[=](int bb,int kk)->float{
        if(kk<E_){int si=(tt==0)?START_:inp[bb*T_+tt-1];return emb[(size_t)si*E_+kk];}
        else if(kk<E_+H_) return e2[bb*H_+kk-E_];
        else if(kk<E_+H_+A_) return a2c[bb*A_+kk-(E_+H_)];
        else{
          int hh=kk-(E_+H_+A_); float s=0.f;
#pragma unroll
          for(int jj=0;jj<6;jj++) s+=sscl[bb*6+jj]*sp[(size_t)(bb*6+jj)*H_+hh];
          return s;
        }
      });
      gld[((usub<<3)|kq)*64+lane]=acc;
      __syncthreads();
      if(w<2&&lane<40){
        int u=blk*2+w;
        float s=0.f;
#pragma unroll
        for(int q=0;q<8;q++) s+=gld[((w<<3)|q)*64+lane];
        float ex=(float)(2*(u>>1))/512.0f;
        float ang=(float)t/powf(10000.0f,ex);
        s+=p.inb[u]+((u&1)?cosf(ang):sinf(ang));
        p.dec[lane*H_+u]=s;
      }
      __syncthreads();
    }
    BARR();

    lstm_ph(p,SH,gld,t,p.r1Wih,H_,p.r1Whh,p.r1b,p.dec ,false,h1r,c1r,h1w,c1w); BARR();
    qk_ph(p,SH,h1w,p.M1T,p.bqk1);                                              BARR();
    scctx_ph(p,SH);                                                            BARR();
    atto_ph(p,SH,p.a1Wv,p.a1bv,false,t);                                       BARR();
    lstm_ph(p,SH,gld,t,p.r2Wih,A_,p.r2Whh,p.r2b,p.att1,false,h2r,c2r,h2w,c2w); BARR();
    qk_ph(p,SH,h2w,p.M2T,p.bqk2);                                              BARR();
    scctx_ph(p,SH);                                                            BARR();
    atto_ph(p,SH,p.a2Wv,p.a2bv,true,t);                                        BARR();
    copyscsel_ph(p,SH,red,t);                                                  BARR();
  }
#undef BARR
}

// vocab logits: one (v-tile, t) per block
__global__ __launch_bounds__(NTHR) void k_vocab(P p){
  __shared__ float SH[10496];
  int tid=threadIdx.x;
  int item=blockIdx.x;
  int vt=item/T_, t=item-vt*T_;
  long v0=(long)vt*256;
  if(v0>=V_) return;
  int vcnt=min(256,(int)(V_-v0));
  int row=tid>>2, qtr=tid&3;
  float acc[10];
#pragma unroll
  for(int q=0;q<10;q++) acc[q]=0.f;
  for(int c=0;c<10;c++){
    int a0=c*32, aw=min(32,A_-a0);
    int awf4=aw>>2;
    __syncthreads();
    for(int i=tid;i<vcnt*awf4;i+=NTHR){
      int vr=i/awf4, f=i-vr*awf4;
      *(float4*)&SH[vr*36+f*4]=*(const float4*)(p.oW+(size_t)(v0+vr)*A_+a0+f*4);
    }
    for(int i=tid;i<aw*40;i+=NTHR) SH[9216+i]=p.attTall[(size_t)t*A_*B_+a0*B_+i];
    __syncthreads();
    if(row<vcnt){
      const float* wrow=&SH[row*36];
      for(int ac=0;ac<aw;ac++){
        float wv=wrow[ac];
        const float2* at=(const float2*)&SH[9216+ac*40+qtr*10];
#pragma unroll
        for(int bq=0;bq<5;bq++){
          float2 t2=at[bq];
          acc[bq*2+0]+=wv*t2.x;
          acc[bq*2+1]+=wv*t2.y;
        }
      }
    }
  }
  if(row<vcnt){
    long v=v0+row;
    float obv=p.ob[v];
#pragma unroll
    for(int bb=0;bb<10;bb++){
      int b=qtr*10+bb;
      p.dout[((size_t)(b*T_+t))*V_+v]=acc[bb]+obv;
    }
  }
}

// deferred scatter adds: one (b,t) per block
__global__ __launch_bounds__(NTHR) void k_scatter(P p){
  __shared__ float SH[1000];
  __shared__ float red[16];
  int tid=threadIdx.x,w=tid>>6,lane=tid&63;
  int b=blockIdx.x/T_, t=blockIdx.x%T_;
  const float* scr=p.sccAll+((size_t)t*B_+b)*L_;
  if(tid<L_) SH[tid]=scr[tid];
  __syncthreads();
  float lm=(tid<L_)?SH[tid]:-3.0e38f;
  lm=wredMax(lm);
  if(lane==0) red[w]=lm;
  __syncthreads();
  float m=red[0];
#pragma unroll
  for(int q=1;q<16;q++) m=fmaxf(m,red[q]);
  __syncthreads();
  float e=(tid<L_)?expf(SH[tid]-m):0.f;
  float ls=wredSum(e);
  if(lane==0) red[w]=ls;
  __syncthreads();
  float S=0.f;
#pragma unroll
  for(int q=0;q<16;q++) S+=red[q];
  float f=p.scale[0]*p.scale[0]/S;
  if(tid<L_)
    atomicAdd(p.dout+((size_t)(b*T_+t))*V_+p.enc_in[b*L_+tid], e*f);
}

// argmax per (b,t): one per block
__global__ __launch_bounds__(NTHR) void k_argmax(P p){
  __shared__ float vs[1024];
  __shared__ int isa[1024];
  int tid=threadIdx.x;
  int b=blockIdx.x/T_, t=blockIdx.x%T_;
  const float* row=p.dout+((size_t)(b*T_+t))*V_;
  float best=-3.0e38f; int bi=0;
  for(int i4=tid;i4<V_/4;i4+=NTHR){
    float4 x=((const float4*)row)[i4];
    int base=i4*4;
    if(x.x>best){best=x.x;bi=base;}
    if(x.y>best){best=x.y;bi=base+1;}
    if(x.z>best){best=x.z;bi=base+2;}
    if(x.w>best){best=x.w;bi=base+3;}
  }
  vs[tid]=best; isa[tid]=bi;
  __syncthreads();
  for(int off=512;off>0;off>>=1){
    if(tid<off){
      float ov=vs[tid+off]; int oi=isa[tid+off];
      if(ov>vs[tid]||(ov==vs[tid]&&oi<isa[tid])){vs[tid]=ov; isa[tid]=oi;}
    }
    __syncthreads();
  }
  if(tid==0) p.dout[(size_t)B_*T_*V_+b*T_+t]=(float)isa[0];
}

extern "C" void kernel_launch(void* const* d_in, const int* in_sizes, int n_in,
                              void* d_out, int out_size, void* d_ws, size_t ws_size,
                              hipStream_t stream){
  P p;
  p.enc_in=(const int*)d_in[0];
  p.enc   =(const float*)d_in[1];
  p.mask  =(const unsigned char*)d_in[2];
  p.inputs=(const int*)d_in[3];
  p.embed =(const float*)d_in[4];
  p.e1Wih=(const float*)d_in[5];  p.e1Whh=(const float*)d_in[6];  p.e1b=(const float*)d_in[7];
  p.e2Wih=(const float*)d_in[8];  p.e2Whh=(const float*)d_in[9];  p.e2b=(const float*)d_in[10];
  p.inW  =(const float*)d_in[11]; p.inb  =(const float*)d_in[12];
  p.r1Wih=(const float*)d_in[13]; p.r1Whh=(const float*)d_in[14]; p.r1b=(const float*)d_in[15];
  p.a1Wq =(const float*)d_in[16]; p.a1bq =(const float*)d_in[17];
  p.a1Wk =(const float*)d_in[18];
  p.a1Wv =(const float*)d_in[20]; p.a1bv =(const float*)d_in[21];
  p.r2Wih=(const float*)d_in[22]; p.r2Whh=(const float*)d_in[23]; p.r2b=(const float*)d_in[24];
  p.a2Wq =(const float*)d_in[25]; p.a2bq =(const float*)d_in[26];
  p.a2Wk =(const float*)d_in[27];
  p.a2Wv =(const float*)d_in[29]; p.a2bv =(const float*)d_in[30];
  p.cW   =(const float*)d_in[31]; p.cb   =(const float*)d_in[32];
  p.oW   =(const float*)d_in[33]; p.ob   =(const float*)d_in[34];
  p.scale=(const float*)d_in[35];
  p.dout=(float*)d_out;

  float* w=(float*)d_ws;
  p.copyKh=(unsigned short*)(w+OFF_CKH);
  p.M1T  =w+OFF_M1T;    p.M2T =w+OFF_M2T;
  p.bqk1 =w+OFF_BQK1;   p.bqk2=w+OFF_BQK2;
  p.qk   =w+OFF_QK;     p.dec =w+OFF_DEC;
  p.att1 =w+OFF_ATT1;
  p.cpart=w+OFF_CPART;  p.cstat=w+OFF_CSTAT;
  p.attTall=w+OFF_ATTA; p.sccAll=w+OFF_SCCA;
  p.stt  =w+OFF_STT;
  p.att2 =w+OFF_ATT2;   p.selp=w+OFF_SELP;
  p.selstat=w+OFF_SELST;
  p.flags=(unsigned*)(w+OFF_FLAGS);
  p.rel  =(unsigned*)(w+OFF_REL);

  // zero: states, att2 carry, sel partials+stats, barrier flags/release
  hipMemsetAsync(w+OFF_STT,0,(WS_END-OFF_STT)*sizeof(float),stream);
  k_rec<<<NBLK,NTHR,0,stream>>>(p);
  k_vocab<<<NVT*T_,NTHR,0,stream>>>(p);
  k_scatter<<<B_*T_,NTHR,0,stream>>>(p);
  k_argmax<<<B_*T_,NTHR,0,stream>>>(p);
}